// Round 6
// baseline (476.126 us; speedup 1.0000x reference)
//
#include <hip/hip_runtime.h>
#include <hip/hip_bf16.h>
#include <math.h>

#define B_ 4
#define M_ 1024
#define NIN 70
#define D_ 256
#define H_ 8
#define L_ 4
#define DFF_ 1024
#define BM_TOT 4096

typedef __hip_bfloat16 bf16;
typedef short short8 __attribute__((ext_vector_type(8)));
typedef float f32x4 __attribute__((ext_vector_type(4)));

// psum layout: [8 slots][BM_TOT rows][2] fp32. Fixed slot->col-range map makes
// the 8-partial sum deterministic in every consumer.

// ---------------- merged: weight convert+transpose (idx<772) | embedding (idx>=772) ----------------
__global__ __launch_bounds__(256) void wconv_embed(
    const float* __restrict__ Wq, const float* __restrict__ Wk, const float* __restrict__ Wv,
    const float* __restrict__ Wo, const float* __restrict__ uw, const float* __restrict__ dw,
    const float* __restrict__ finw,
    bf16* __restrict__ wqkvt, bf16* __restrict__ wot, bf16* __restrict__ uwt,
    bf16* __restrict__ dwt, bf16* __restrict__ fwt,
    const float* __restrict__ X, const float* __restrict__ fW, const float* __restrict__ fb,
    const float* __restrict__ cW, const float* __restrict__ cb,
    float* __restrict__ x, float* __restrict__ psum)
{
  __shared__ float T[64][65];
  __shared__ float xr[4][NIN];
  __shared__ float red[4][4][2];
  int idx = blockIdx.x;
  int t = threadIdx.x;
  if (idx >= 772) {
    // ---- embedding: 4 rows/block + ln1(0) stats to psum ----
    int bm0 = (idx - 772) * 4;
    int d = t;
    for (int i = d; i < 4 * NIN; i += 256)
      xr[i / NIN][i % NIN] = X[(size_t)(bm0 + i / NIN) * NIN + i % NIN];
    __syncthreads();
    int f = d & 127;
    float fw0 = fW[f * 3 + 0], fw1 = fW[f * 3 + 1], fw2 = fW[f * 3 + 2], fbv = fb[f];
    float cbv = cb[d];
    float acc[4];
    #pragma unroll
    for (int r = 0; r < 4; ++r) {
      float proj = xr[r][0] * fw0 + xr[r][1] * fw1 + xr[r][2] * fw2 + fbv;
      acc[r] = (d < 128 ? cosf(proj) : sinf(proj)) * 0.17677669529663687f + cbv;
    }
    #pragma unroll 8
    for (int c = 0; c < 64; ++c) {
      float cw = cW[c * D_ + d];
      #pragma unroll
      for (int r = 0; r < 4; ++r) acc[r] += xr[r][6 + c] * cw;
    }
    #pragma unroll
    for (int r = 0; r < 4; ++r)
      x[(size_t)(bm0 + r) * D_ + d] = acc[r];
    // stats: full row sums -> slot 0; zeros -> slots 1..7
    int wave = d >> 6, lane = d & 63;
    #pragma unroll
    for (int r = 0; r < 4; ++r) {
      float s = acc[r], qq = acc[r] * acc[r];
      #pragma unroll
      for (int off = 32; off; off >>= 1) {
        s += __shfl_xor(s, off, 64);
        qq += __shfl_xor(qq, off, 64);
      }
      if (lane == 0) { red[wave][r][0] = s; red[wave][r][1] = qq; }
    }
    __syncthreads();
    if (t < 8) {
      int r = t >> 1, c = t & 1;
      float v = red[0][r][c] + red[1][r][c] + red[2][r][c] + red[3][r][c];
      psum[((size_t)0 * BM_TOT + bm0 + r) * 2 + c] = v;
    } else if (t < 64) {
      int i = t - 8;                 // 56 entries: slots 1..7 x 4 rows x 2
      int slot = 1 + i / 8; int rr = (i & 7) >> 1; int c = i & 1;
      psum[((size_t)slot * BM_TOT + bm0 + rr) * 2 + c] = 0.f;
    }
    return;
  }
  // ---- weight convert ----
  const float* src; bf16* dst; int K, N, k0, n0, rbase, S;
  if (idx < 192) {            // Wq/Wk/Wv -> wqkvt[l][m*256 + n][k]
    int m = idx >> 6; int r = idx & 63; int l = r >> 4; int tt = r & 15;
    int kt = tt >> 2, nt = tt & 3;
    src = (m == 0 ? Wq : (m == 1 ? Wk : Wv)) + (size_t)l * 65536;
    K = 256; N = 256; k0 = kt * 64; n0 = nt * 64;
    dst = wqkvt + (size_t)l * 196608; rbase = m * 256 + nt * 64; S = 256;
  } else if (idx < 256) {     // Wo
    int r = idx - 192; int l = r >> 4; int tt = r & 15; int kt = tt >> 2, nt = tt & 3;
    src = Wo + (size_t)l * 65536; K = 256; N = 256; k0 = kt * 64; n0 = nt * 64;
    dst = wot + (size_t)l * 65536; rbase = nt * 64; S = 256;
  } else if (idx < 512) {     // uw (256 x 1024)
    int r = idx - 256; int l = r >> 6; int tt = r & 63; int kt = tt >> 4, nt = tt & 15;
    src = uw + (size_t)l * 262144; K = 256; N = 1024; k0 = kt * 64; n0 = nt * 64;
    dst = uwt + (size_t)l * 262144; rbase = nt * 64; S = 256;
  } else if (idx < 768) {     // dw (1024 x 256)
    int r = idx - 512; int l = r >> 6; int tt = r & 63; int kt = tt >> 2, nt = tt & 3;
    src = dw + (size_t)l * 262144; K = 1024; N = 256; k0 = kt * 64; n0 = nt * 64;
    dst = dwt + (size_t)l * 262144; rbase = nt * 64; S = 1024;
  } else {                    // finw (256 x 64)
    int kt = idx - 768;
    src = finw; K = 256; N = 64; k0 = kt * 64; n0 = 0;
    dst = fwt; rbase = 0; S = 256;
  }
  int kl = t >> 2, ns = (t & 3) * 16;
  #pragma unroll
  for (int i = 0; i < 16; i += 4)
    *(float4*)&T[kl][ns + i] = *(const float4*)&src[(size_t)(k0 + kl) * N + n0 + ns + i];
  __syncthreads();
  int nl = t >> 2, ks = (t & 3) * 16;
  __align__(16) bf16 tmp[16];
  #pragma unroll
  for (int i = 0; i < 16; ++i) tmp[i] = __float2bfloat16(T[ks + i][nl]);
  *(uint4*)&dst[(size_t)(rbase + nl) * S + k0 + ks] = *(uint4*)&tmp[0];
  *(uint4*)&dst[(size_t)(rbase + nl) * S + k0 + ks + 8] = *(uint4*)&tmp[8];
}

// ---------------- MFMA GEMM, 512 thr / 8 waves, optional LN-partial epilogue ----------------
// flags: 1 gelu, 2 +Res, 4 Cb(bf16), 8 Cf(fp32), 16 write psum partial stats.
__global__ __launch_bounds__(512) void mgemm512(const bf16* __restrict__ Ab,
    const bf16* __restrict__ Wt, const float* __restrict__ bias,
    const float* __restrict__ Res, float* __restrict__ Cf, bf16* __restrict__ Cb,
    float* __restrict__ psum, int K, int N, int flags)
{
  __shared__ short As[64][40];
  __shared__ short Bs[64][40];
  int t = threadIdx.x;
  int m0 = blockIdx.y * 64, n0 = blockIdx.x * 64;
  int w = t >> 6, lane = t & 63;
  int l16 = lane & 15, quad = lane >> 4;
  int s = t & 255;
  int srow = s >> 2, sseg = s & 3;
  bool isA = (t < 256);
  short (*S)[40] = isA ? As : Bs;
  const bf16* pS = (isA ? Ab + (size_t)(m0 + srow) * K
                        : Wt + (size_t)(n0 + srow) * K) + sseg * 8;
  uint4 ra = *(const uint4*)pS;
  f32x4 acc[2] = {{0.f,0.f,0.f,0.f},{0.f,0.f,0.f,0.f}};
  int mf = (w & 3) * 16 + l16;
  int kf = quad * 8;
  int ntb = (w >> 2) * 2;
  for (int k0 = 0; k0 < K; k0 += 32) {
    *(uint4*)&S[srow][sseg * 8] = ra;
    __syncthreads();
    if (k0 + 32 < K) ra = *(const uint4*)(pS + k0 + 32);
    short8 a = *(short8*)&As[mf][kf];
    #pragma unroll
    for (int i = 0; i < 2; ++i) {
      short8 bfr = *(short8*)&Bs[(ntb + i) * 16 + l16][kf];
      acc[i] = __builtin_amdgcn_mfma_f32_16x16x32_bf16(a, bfr, acc[i], 0, 0, 0);
    }
    __syncthreads();
  }
  int row0 = m0 + (w & 3) * 16 + quad * 4;
  float vv[2][4];
  #pragma unroll
  for (int i = 0; i < 2; ++i) {
    int col = n0 + (ntb + i) * 16 + l16;
    float bs = bias[col];
    #pragma unroll
    for (int r = 0; r < 4; ++r) {
      float v = acc[i][r] + bs;
      if (flags & 1) v = 0.5f * v * (1.0f + erff(v * 0.70710678118654752f));
      if (flags & 2) v += Res[(size_t)(row0 + r) * N + col];
      vv[i][r] = v;
      if (flags & 8) Cf[(size_t)(row0 + r) * N + col] = v;
      if (flags & 4) Cb[(size_t)(row0 + r) * N + col] = __float2bfloat16(v);
    }
  }
  if (flags & 16) {
    int slot = blockIdx.x * 2 + (w >> 2);
    #pragma unroll
    for (int r = 0; r < 4; ++r) {
      float sv = vv[0][r] + vv[1][r];
      float sq = vv[0][r] * vv[0][r] + vv[1][r] * vv[1][r];
      #pragma unroll
      for (int off = 1; off < 16; off <<= 1) {
        sv += __shfl_xor(sv, off, 64);
        sq += __shfl_xor(sq, off, 64);
      }
      if (l16 == 0) {
        psum[((size_t)slot * BM_TOT + row0 + r) * 2 + 0] = sv;
        psum[((size_t)slot * BM_TOT + row0 + r) * 2 + 1] = sq;
      }
    }
  }
}

// ---------------- QKV GEMM, A = LN(x) applied inline from psum stats ----------------
__global__ __launch_bounds__(256) void mgemm_qkv_ln(const float* __restrict__ xf,
    const float* __restrict__ psum, const bf16* __restrict__ Wt,
    const float* __restrict__ lw, const float* __restrict__ lb,
    const float* __restrict__ bq, const float* __restrict__ bk, const float* __restrict__ bv,
    bf16* __restrict__ qo, bf16* __restrict__ ko, bf16* __restrict__ vo)
{
  __shared__ short As[64][40];
  __shared__ short Bs[64][40];
  int t = threadIdx.x;
  int m0 = blockIdx.y * 64, n0g = blockIdx.x * 64;
  int w = t >> 6, lane = t & 63;
  int srow = t >> 2, sseg = t & 3;
  int gr = m0 + srow;
  float sv = 0.f, sq = 0.f;
  #pragma unroll
  for (int i = 0; i < 8; ++i) {
    float2 p = *(const float2*)&psum[((size_t)i * BM_TOT + gr) * 2];
    sv += p.x; sq += p.y;
  }
  float mu = sv * (1.0f / D_);
  float rstd = rsqrtf(sq * (1.0f / D_) - mu * mu + 1e-5f);
  int c0 = sseg * 8;
  const float* pX = xf + (size_t)gr * D_;
  const bf16* pB = Wt + (size_t)(n0g + srow) * 256 + c0;
  float4 xa = *(const float4*)(pX + c0);
  float4 xb = *(const float4*)(pX + c0 + 4);
  uint4 rb = *(const uint4*)pB;
  f32x4 acc[4] = {{0.f,0.f,0.f,0.f},{0.f,0.f,0.f,0.f},{0.f,0.f,0.f,0.f},{0.f,0.f,0.f,0.f}};
  int mf = w * 16 + (lane & 15);
  int kf = (lane >> 4) * 8;
  for (int k0 = 0; k0 < 256; k0 += 32) {
    int c = k0 + c0;
    float4 wa = *(const float4*)(lw + c);
    float4 wb = *(const float4*)(lw + c + 4);
    float4 ba = *(const float4*)(lb + c);
    float4 bb = *(const float4*)(lb + c + 4);
    __align__(16) bf16 tb[8];
    tb[0] = __float2bfloat16((xa.x - mu) * rstd * wa.x + ba.x);
    tb[1] = __float2bfloat16((xa.y - mu) * rstd * wa.y + ba.y);
    tb[2] = __float2bfloat16((xa.z - mu) * rstd * wa.z + ba.z);
    tb[3] = __float2bfloat16((xa.w - mu) * rstd * wa.w + ba.w);
    tb[4] = __float2bfloat16((xb.x - mu) * rstd * wb.x + bb.x);
    tb[5] = __float2bfloat16((xb.y - mu) * rstd * wb.y + bb.y);
    tb[6] = __float2bfloat16((xb.z - mu) * rstd * wb.z + bb.z);
    tb[7] = __float2bfloat16((xb.w - mu) * rstd * wb.w + bb.w);
    *(uint4*)&As[srow][c0] = *(uint4*)tb;
    *(uint4*)&Bs[srow][c0] = rb;
    __syncthreads();
    if (k0 + 32 < 256) {
      xa = *(const float4*)(pX + c + 32);
      xb = *(const float4*)(pX + c + 36);
      rb = *(const uint4*)(pB + k0 + 32);
    }
    short8 a = *(short8*)&As[mf][kf];
    #pragma unroll
    for (int nt = 0; nt < 4; ++nt) {
      short8 bfr = *(short8*)&Bs[nt * 16 + (lane & 15)][kf];
      acc[nt] = __builtin_amdgcn_mfma_f32_16x16x32_bf16(a, bfr, acc[nt], 0, 0, 0);
    }
    __syncthreads();
  }
  int seg = n0g >> 8;
  const float* bbv = (seg == 0 ? bq : (seg == 1 ? bk : bv));
  bf16* dst = (seg == 0 ? qo : (seg == 1 ? ko : vo));
  int row0 = m0 + w * 16 + (lane >> 4) * 4;
  #pragma unroll
  for (int nt = 0; nt < 4; ++nt) {
    int col = (n0g & 255) + nt * 16 + (lane & 15);
    float bs = bbv[col];
    #pragma unroll
    for (int r = 0; r < 4; ++r)
      dst[(size_t)(row0 + r) * 256 + col] = __float2bfloat16(acc[nt][r] + bs);
  }
}

// ---------------- GEMM, A = LN(x) applied inline (K=256); used for uw and fin ----------------
__global__ __launch_bounds__(256) void mgemmA_ln(const float* __restrict__ xf,
    const float* __restrict__ psum, const bf16* __restrict__ Wt,
    const float* __restrict__ lw, const float* __restrict__ lb,
    const float* __restrict__ bias, float* __restrict__ Cf, bf16* __restrict__ Cb,
    int N, int flags)
{
  __shared__ short As[64][40];
  __shared__ short Bs[64][40];
  int t = threadIdx.x;
  int m0 = blockIdx.y * 64, n0 = blockIdx.x * 64;
  int w = t >> 6, lane = t & 63;
  int srow = t >> 2, sseg = t & 3;
  int gr = m0 + srow;
  float sv = 0.f, sq = 0.f;
  #pragma unroll
  for (int i = 0; i < 8; ++i) {
    float2 p = *(const float2*)&psum[((size_t)i * BM_TOT + gr) * 2];
    sv += p.x; sq += p.y;
  }
  float mu = sv * (1.0f / D_);
  float rstd = rsqrtf(sq * (1.0f / D_) - mu * mu + 1e-5f);
  int c0 = sseg * 8;
  const float* pX = xf + (size_t)gr * D_;
  const bf16* pB = Wt + (size_t)(n0 + srow) * 256 + c0;
  float4 xa = *(const float4*)(pX + c0);
  float4 xb = *(const float4*)(pX + c0 + 4);
  uint4 rb = *(const uint4*)pB;
  f32x4 acc[4] = {{0.f,0.f,0.f,0.f},{0.f,0.f,0.f,0.f},{0.f,0.f,0.f,0.f},{0.f,0.f,0.f,0.f}};
  int mf = w * 16 + (lane & 15);
  int kf = (lane >> 4) * 8;
  for (int k0 = 0; k0 < 256; k0 += 32) {
    int c = k0 + c0;
    float4 wa = *(const float4*)(lw + c);
    float4 wb = *(const float4*)(lw + c + 4);
    float4 ba = *(const float4*)(lb + c);
    float4 bb = *(const float4*)(lb + c + 4);
    __align__(16) bf16 tb[8];
    tb[0] = __float2bfloat16((xa.x - mu) * rstd * wa.x + ba.x);
    tb[1] = __float2bfloat16((xa.y - mu) * rstd * wa.y + ba.y);
    tb[2] = __float2bfloat16((xa.z - mu) * rstd * wa.z + ba.z);
    tb[3] = __float2bfloat16((xa.w - mu) * rstd * wa.w + ba.w);
    tb[4] = __float2bfloat16((xb.x - mu) * rstd * wb.x + bb.x);
    tb[5] = __float2bfloat16((xb.y - mu) * rstd * wb.y + bb.y);
    tb[6] = __float2bfloat16((xb.z - mu) * rstd * wb.z + bb.z);
    tb[7] = __float2bfloat16((xb.w - mu) * rstd * wb.w + bb.w);
    *(uint4*)&As[srow][c0] = *(uint4*)tb;
    *(uint4*)&Bs[srow][c0] = rb;
    __syncthreads();
    if (k0 + 32 < 256) {
      xa = *(const float4*)(pX + c + 32);
      xb = *(const float4*)(pX + c + 36);
      rb = *(const uint4*)(pB + k0 + 32);
    }
    short8 a = *(short8*)&As[mf][kf];
    #pragma unroll
    for (int nt = 0; nt < 4; ++nt) {
      short8 bfr = *(short8*)&Bs[nt * 16 + (lane & 15)][kf];
      acc[nt] = __builtin_amdgcn_mfma_f32_16x16x32_bf16(a, bfr, acc[nt], 0, 0, 0);
    }
    __syncthreads();
  }
  int row0 = m0 + w * 16 + (lane >> 4) * 4;
  #pragma unroll
  for (int nt = 0; nt < 4; ++nt) {
    int col = n0 + nt * 16 + (lane & 15);
    float bs = bias[col];
    #pragma unroll
    for (int r = 0; r < 4; ++r) {
      float v = acc[nt][r] + bs;
      if (flags & 1) v = 0.5f * v * (1.0f + erff(v * 0.70710678118654752f));
      if (flags & 8) Cf[(size_t)(row0 + r) * N + col] = v;
      if (flags & 4) Cb[(size_t)(row0 + r) * N + col] = __float2bfloat16(v);
    }
  }
}

// ---------------- MFMA flash attention (unchanged) ----------------
__global__ __launch_bounds__(256) void k_flash(const bf16* __restrict__ q,
    const bf16* __restrict__ k, const bf16* __restrict__ v, bf16* __restrict__ o)
{
  int qt = blockIdx.x, h = blockIdx.y, b = blockIdx.z;
  int t = threadIdx.x;
  int w = t >> 6, lane = t & 63;
  int quad = lane >> 4, l16 = lane & 15;
  __shared__ short Ks[64][40];
  __shared__ short Vt[32][76];
  __shared__ short Pl[4][16][72];
  short8 a_q = *(const short8*)&q[((size_t)(b * M_) + qt * 64 + w * 16 + l16) * D_ + h * 32 + quad * 8];
  f32x4 o_acc[2] = {{0.f,0.f,0.f,0.f},{0.f,0.f,0.f,0.f}};
  float l_acc[4] = {0.f, 0.f, 0.f, 0.f};
  int skey = t >> 2, sseg = t & 3;
  const float scale = 0.17677669529663687f;
  for (int kt = 0; kt < 16; ++kt) {
    __syncthreads();
    *(short8*)&Ks[skey][sseg * 8] =
        *(const short8*)&k[((size_t)(b * M_) + kt * 64 + skey) * D_ + h * 32 + sseg * 8];
    short8 vv = *(const short8*)&v[((size_t)(b * M_) + kt * 64 + skey) * D_ + h * 32 + sseg * 8];
    #pragma unroll
    for (int i = 0; i < 8; ++i) Vt[sseg * 8 + i][skey] = vv[i];
    __syncthreads();
    #pragma unroll
    for (int st = 0; st < 4; ++st) {
      short8 bf = *(short8*)&Ks[st * 16 + l16][quad * 8];
      f32x4 s4 = __builtin_amdgcn_mfma_f32_16x16x32_bf16(a_q, bf, (f32x4){0.f,0.f,0.f,0.f}, 0, 0, 0);
      #pragma unroll
      for (int r = 0; r < 4; ++r) {
        float p = __expf(s4[r] * scale);
        l_acc[r] += p;
        bf16 hb = __float2bfloat16(p);
        Pl[w][quad * 4 + r][st * 16 + l16] = *reinterpret_cast<short*>(&hb);
      }
    }
    asm volatile("s_waitcnt lgkmcnt(0)" ::: "memory");
    #pragma unroll
    for (int kh = 0; kh < 2; ++kh) {
      short8 a_p = *(short8*)&Pl[w][l16][kh * 32 + quad * 8];
      #pragma unroll
      for (int nt = 0; nt < 2; ++nt) {
        short8 b_v = *(short8*)&Vt[nt * 16 + l16][kh * 32 + quad * 8];
        o_acc[nt] = __builtin_amdgcn_mfma_f32_16x16x32_bf16(a_p, b_v, o_acc[nt], 0, 0, 0);
      }
    }
  }
  #pragma unroll
  for (int r = 0; r < 4; ++r) {
    float lv = l_acc[r];
    lv += __shfl_xor(lv, 1, 64);
    lv += __shfl_xor(lv, 2, 64);
    lv += __shfl_xor(lv, 4, 64);
    lv += __shfl_xor(lv, 8, 64);
    l_acc[r] = 1.0f / lv;
  }
  #pragma unroll
  for (int nt = 0; nt < 2; ++nt)
    #pragma unroll
    for (int r = 0; r < 4; ++r)
      o[((size_t)(b * M_) + qt * 64 + w * 16 + quad * 4 + r) * D_ + h * 32 + nt * 16 + l16] =
          __float2bfloat16(o_acc[nt][r] * l_acc[r]);
}

// ---------------- s head stage 1 (unchanged) ----------------
__global__ __launch_bounds__(256) void k_shead1(const bf16* __restrict__ q3,
    const bf16* __restrict__ k3, const float* __restrict__ snw, const float* __restrict__ snb,
    const float* __restrict__ sfw, const float* __restrict__ sfb, float* __restrict__ stmp)
{
  int ct = blockIdx.x, rt = blockIdx.y, b = blockIdx.z;
  int t = threadIdx.x;
  int w = t >> 6, lane = t & 63;
  int quad = lane >> 4, l16 = lane & 15;
  const float scale = 0.17677669529663687f;
  float wsn[H_], bsn[H_], wsf[H_];
  #pragma unroll
  for (int h = 0; h < H_; ++h) { wsn[h] = snw[h]; bsn[h] = snb[h]; wsf[h] = sfw[h]; }
  float bias0 = sfb[0];
  short8 aqs[H_];
  #pragma unroll
  for (int h = 0; h < H_; ++h)
    aqs[h] = *(const short8*)&q3[((size_t)(b * M_) + rt * 64 + w * 16 + l16) * D_ + h * 32 + quad * 8];
  #pragma unroll
  for (int cf = 0; cf < 4; ++cf) {
    f32x4 s4[H_];
    #pragma unroll
    for (int h = 0; h < H_; ++h) {
      short8 bk = *(const short8*)&k3[((size_t)(b * M_) + ct * 64 + cf * 16 + l16) * D_ + h * 32 + quad * 8];
      s4[h] = __builtin_amdgcn_mfma_f32_16x16x32_bf16(aqs[h], bk, (f32x4){0.f,0.f,0.f,0.f}, 0, 0, 0);
    }
    #pragma unroll
    for (int r = 0; r < 4; ++r) {
      float d8[H_], ssum = 0.f, ssq = 0.f;
      #pragma unroll
      for (int h = 0; h < H_; ++h) {
        float s = s4[h][r] * scale;
        d8[h] = s; ssum += s; ssq += s * s;
      }
      float mu = ssum * 0.125f;
      float var = ssq * 0.125f - mu * mu;
      float rstd = rsqrtf(var + 1e-5f);
      float val = bias0;
      #pragma unroll
      for (int h = 0; h < H_; ++h)
        val += ((d8[h] - mu) * rstd * wsn[h] + bsn[h]) * wsf[h];
      stmp[((size_t)(b * M_) + rt * 64 + w * 16 + quad * 4 + r) * M_ + ct * 64 + cf * 16 + l16] = val;
    }
  }
}

// ---------------- s head stage 2: symmetrize (unchanged) ----------------
__global__ __launch_bounds__(256) void k_sym(const float* __restrict__ stmp,
    float* __restrict__ outs)
{
  int ct = blockIdx.x, rt = blockIdx.y, b = blockIdx.z;
  __shared__ float Tb[64][68];
  int t = threadIdx.x;
  int row = t >> 2, seg = (t & 3) * 16;
  const float* srcB = stmp + ((size_t)(b * M_) + ct * 64 + row) * M_ + rt * 64 + seg;
  #pragma unroll
  for (int i = 0; i < 16; i += 4) {
    float4 v = *(const float4*)(srcB + i);
    Tb[seg + i + 0][row] = v.x;
    Tb[seg + i + 1][row] = v.y;
    Tb[seg + i + 2][row] = v.z;
    Tb[seg + i + 3][row] = v.w;
  }
  __syncthreads();
  const float* srcA = stmp + ((size_t)(b * M_) + rt * 64 + row) * M_ + ct * 64 + seg;
  float* dst = outs + ((size_t)(b * M_) + rt * 64 + row) * M_ + ct * 64 + seg;
  #pragma unroll
  for (int i = 0; i < 16; i += 4) {
    float4 a = *(const float4*)(srcA + i);
    float4 tv = *(const float4*)&Tb[row][seg + i];
    float4 o;
    o.x = 0.5f * (a.x + tv.x);
    o.y = 0.5f * (a.y + tv.y);
    o.z = 0.5f * (a.z + tv.z);
    o.w = 0.5f * (a.w + tv.w);
    *(float4*)(dst + i) = o;
  }
}

extern "C" void kernel_launch(void* const* d_in, const int* in_sizes, int n_in,
                              void* d_out, int out_size, void* d_ws, size_t ws_size,
                              hipStream_t stream)
{
  const float* X    = (const float*)d_in[0];
  const float* fW   = (const float*)d_in[2];
  const float* fb   = (const float*)d_in[3];
  const float* cW   = (const float*)d_in[4];
  const float* cb   = (const float*)d_in[5];
  const float* Wq   = (const float*)d_in[6];
  const float* bq   = (const float*)d_in[7];
  const float* Wk   = (const float*)d_in[8];
  const float* bk   = (const float*)d_in[9];
  const float* Wv   = (const float*)d_in[10];
  const float* bv   = (const float*)d_in[11];
  const float* Wo   = (const float*)d_in[12];
  const float* bo   = (const float*)d_in[13];
  const float* ln1w = (const float*)d_in[14];
  const float* ln1b = (const float*)d_in[15];
  const float* ln2w = (const float*)d_in[16];
  const float* ln2b = (const float*)d_in[17];
  const float* lnfw = (const float*)d_in[18];
  const float* lnfb = (const float*)d_in[19];
  const float* uw   = (const float*)d_in[20];
  const float* ub   = (const float*)d_in[21];
  const float* dw   = (const float*)d_in[22];
  const float* db   = (const float*)d_in[23];
  const float* finw = (const float*)d_in[24];
  const float* finb = (const float*)d_in[25];
  const float* snw  = (const float*)d_in[26];
  const float* snb  = (const float*)d_in[27];
  const float* sfw  = (const float*)d_in[28];
  const float* sfb  = (const float*)d_in[29];

  char* base = (char*)d_ws;
  const size_t MiB = 1024 * 1024;
  bf16* q_b   = (bf16*)(base + 0 * MiB);              // layer-3 q lives until s head
  bf16* k_b   = (bf16*)(base + 2 * MiB);              // layer-3 k lives until s head
  bf16* wqkvt = (bf16*)(base + 4 * MiB);              // 1.5 MiB
  bf16* wot   = (bf16*)(base + 5 * MiB + 512 * 1024); // 512 KiB
  bf16* uwt   = (bf16*)(base + 6 * MiB);              // 2 MiB
  bf16* dwt   = (bf16*)(base + 8 * MiB);              // 2 MiB
  bf16* fwt   = (bf16*)(base + 10 * MiB);             // 32 KiB
  float* x    = (float*)(base + 10 * MiB + 512 * 1024); // 4 MiB
  char* SR    = base + 14 * MiB + 512 * 1024;
  bf16* v_b   = (bf16*)(SR + 2 * MiB);
  bf16* att_b = (bf16*)(SR + 4 * MiB);
  bf16* h1_b  = (bf16*)(SR + 6 * MiB);                // 8 MiB
  float* psum = (float*)(base + 30 * MiB);            // 256 KiB LN partial stats
  float* stmp = (float*)(base + 32 * MiB);            // 16 MiB raw s scores
  float* outx = (float*)d_out;
  float* outs = outx + (size_t)BM_TOT * 64;

  dim3 blk(256);
  dim3 blk512(512);
  wconv_embed<<<dim3(772 + BM_TOT / 4), blk, 0, stream>>>(
      Wq, Wk, Wv, Wo, uw, dw, finw, wqkvt, wot, uwt, dwt, fwt,
      X, fW, fb, cW, cb, x, psum);
  for (int l = 0; l < L_; ++l) {
    // qkv = ln1(x) @ Wqkv + b   (LN applied inline from psum)
    mgemm_qkv_ln<<<dim3(12, 64), blk, 0, stream>>>(x, psum, wqkvt + (size_t)l * 196608,
                                                   ln1w + l * D_, ln1b + l * D_,
                                                   bq + l * D_, bk + l * D_, bv + l * D_,
                                                   q_b, k_b, v_b);
    k_flash<<<dim3(16, H_, B_), blk, 0, stream>>>(q_b, k_b, v_b, att_b);
    // x += att @ Wo + bo ; psum <- ln2 partial stats
    mgemm512<<<dim3(4, 64), blk512, 0, stream>>>(att_b, wot + (size_t)l * 65536, bo + l * D_,
                                                 x, x, nullptr, psum, 256, 256, 2 | 8 | 16);
    // h1 = gelu(ln2(x) @ uw + ub)   (LN inline)
    mgemmA_ln<<<dim3(16, 64), blk, 0, stream>>>(x, psum, uwt + (size_t)l * 262144,
                                                ln2w + l * D_, ln2b + l * D_,
                                                ub + l * DFF_, nullptr, h1_b, 1024, 1 | 4);
    // x += h1 @ dw + db ; psum <- next ln1 / lnf partial stats
    mgemm512<<<dim3(4, 64), blk512, 0, stream>>>(h1_b, dwt + (size_t)l * 262144, db + l * D_,
                                                 x, x, nullptr, psum, 1024, 256, 2 | 8 | 16);
  }
  // outx = lnf(x) @ finw + finb   (LN inline)
  mgemmA_ln<<<dim3(1, 64), blk, 0, stream>>>(x, psum, fwt, lnfw, lnfb,
                                             finb, outx, nullptr, 64, 8);
  // layer-3 q/k still live in q_b/k_b
  k_shead1<<<dim3(16, 16, B_), blk, 0, stream>>>(q_b, k_b, snw, snb, sfw, sfb, stmp);
  k_sym<<<dim3(16, 16, B_), blk, 0, stream>>>(stmp, outs);
}

// Round 7
// 437.005 us; speedup vs baseline: 1.0895x; 1.0895x over previous
//
#include <hip/hip_runtime.h>
#include <hip/hip_bf16.h>
#include <math.h>

#define B_ 4
#define M_ 1024
#define NIN 70
#define D_ 256
#define H_ 8
#define L_ 4
#define DFF_ 1024
#define BM_TOT 4096

typedef __hip_bfloat16 bf16;
typedef short short8 __attribute__((ext_vector_type(8)));
typedef float f32x4 __attribute__((ext_vector_type(4)));

// ---------------- single-launch weight convert+transpose ----------------
__global__ __launch_bounds__(256) void wconv_all(
    const float* __restrict__ Wq, const float* __restrict__ Wk, const float* __restrict__ Wv,
    const float* __restrict__ Wo, const float* __restrict__ uw, const float* __restrict__ dw,
    const float* __restrict__ finw,
    bf16* __restrict__ wqkvt, bf16* __restrict__ wot, bf16* __restrict__ uwt,
    bf16* __restrict__ dwt, bf16* __restrict__ fwt)
{
  __shared__ float T[64][65];
  int idx = blockIdx.x;
  const float* src; bf16* dst; int K, N, k0, n0, rbase, S;
  if (idx < 192) {            // Wq/Wk/Wv -> wqkvt[l][m*256 + n][k]
    int m = idx >> 6; int r = idx & 63; int l = r >> 4; int tt = r & 15;
    int kt = tt >> 2, nt = tt & 3;
    src = (m == 0 ? Wq : (m == 1 ? Wk : Wv)) + (size_t)l * 65536;
    K = 256; N = 256; k0 = kt * 64; n0 = nt * 64;
    dst = wqkvt + (size_t)l * 196608; rbase = m * 256 + nt * 64; S = 256;
  } else if (idx < 256) {     // Wo
    int r = idx - 192; int l = r >> 4; int tt = r & 15; int kt = tt >> 2, nt = tt & 3;
    src = Wo + (size_t)l * 65536; K = 256; N = 256; k0 = kt * 64; n0 = nt * 64;
    dst = wot + (size_t)l * 65536; rbase = nt * 64; S = 256;
  } else if (idx < 512) {     // uw (256 x 1024)
    int r = idx - 256; int l = r >> 6; int tt = r & 63; int kt = tt >> 4, nt = tt & 15;
    src = uw + (size_t)l * 262144; K = 256; N = 1024; k0 = kt * 64; n0 = nt * 64;
    dst = uwt + (size_t)l * 262144; rbase = nt * 64; S = 256;
  } else if (idx < 768) {     // dw (1024 x 256)
    int r = idx - 512; int l = r >> 6; int tt = r & 63; int kt = tt >> 2, nt = tt & 3;
    src = dw + (size_t)l * 262144; K = 1024; N = 256; k0 = kt * 64; n0 = nt * 64;
    dst = dwt + (size_t)l * 262144; rbase = nt * 64; S = 1024;
  } else {                    // finw (256 x 64)
    int kt = idx - 768;
    src = finw; K = 256; N = 64; k0 = kt * 64; n0 = 0;
    dst = fwt; rbase = 0; S = 256;
  }
  int t = threadIdx.x;
  int kl = t >> 2, ns = (t & 3) * 16;
  #pragma unroll
  for (int i = 0; i < 16; i += 4)
    *(float4*)&T[kl][ns + i] = *(const float4*)&src[(size_t)(k0 + kl) * N + n0 + ns + i];
  __syncthreads();
  int nl = t >> 2, ks = (t & 3) * 16;
  __align__(16) bf16 tmp[16];
  #pragma unroll
  for (int i = 0; i < 16; ++i) tmp[i] = __float2bfloat16(T[ks + i][nl]);
  *(uint4*)&dst[(size_t)(rbase + nl) * S + k0 + ks] = *(uint4*)&tmp[0];
  *(uint4*)&dst[(size_t)(rbase + nl) * S + k0 + ks + 8] = *(uint4*)&tmp[8];
}

// ---------------- embedding: 4 rows/block ----------------
__global__ __launch_bounds__(256) void k_embed(const float* __restrict__ X,
    const float* __restrict__ fW, const float* __restrict__ fb,
    const float* __restrict__ cW, const float* __restrict__ cb,
    float* __restrict__ x)
{
  int bm0 = blockIdx.x * 4;
  int d = threadIdx.x;
  __shared__ float xr[4][NIN];
  for (int i = d; i < 4 * NIN; i += 256)
    xr[i / NIN][i % NIN] = X[(size_t)(bm0 + i / NIN) * NIN + i % NIN];
  __syncthreads();
  int f = d & 127;
  float fw0 = fW[f * 3 + 0], fw1 = fW[f * 3 + 1], fw2 = fW[f * 3 + 2], fbv = fb[f];
  float cbv = cb[d];
  float acc[4];
  #pragma unroll
  for (int r = 0; r < 4; ++r) {
    float proj = xr[r][0] * fw0 + xr[r][1] * fw1 + xr[r][2] * fw2 + fbv;
    acc[r] = (d < 128 ? cosf(proj) : sinf(proj)) * 0.17677669529663687f + cbv;
  }
  #pragma unroll 8
  for (int c = 0; c < 64; ++c) {
    float cw = cW[c * D_ + d];
    #pragma unroll
    for (int r = 0; r < 4; ++r) acc[r] += xr[r][6 + c] * cw;
  }
  #pragma unroll
  for (int r = 0; r < 4; ++r)
    x[(size_t)(bm0 + r) * D_ + d] = acc[r];
}

// ---------------- layernorm: fp32 in -> bf16 out ----------------
__global__ __launch_bounds__(256) void k_ln(const float* __restrict__ xin,
    const float* __restrict__ w, const float* __restrict__ b, bf16* __restrict__ xout)
{
  int wave = threadIdx.x >> 6;
  int lane = threadIdx.x & 63;
  int row = blockIdx.x * 4 + wave;
  float4 xv = *(const float4*)&xin[row * D_ + lane * 4];
  float s = xv.x + xv.y + xv.z + xv.w;
  float q = xv.x * xv.x + xv.y * xv.y + xv.z * xv.z + xv.w * xv.w;
  #pragma unroll
  for (int off = 32; off; off >>= 1) {
    s += __shfl_xor(s, off, 64);
    q += __shfl_xor(q, off, 64);
  }
  float mu = s * (1.0f / D_);
  float var = q * (1.0f / D_) - mu * mu;
  float rstd = rsqrtf(var + 1e-5f);
  float4 wv = *(const float4*)&w[lane * 4];
  float4 bv = *(const float4*)&b[lane * 4];
  __align__(8) bf16 tmp[4];
  tmp[0] = __float2bfloat16((xv.x - mu) * rstd * wv.x + bv.x);
  tmp[1] = __float2bfloat16((xv.y - mu) * rstd * wv.y + bv.y);
  tmp[2] = __float2bfloat16((xv.z - mu) * rstd * wv.z + bv.z);
  tmp[3] = __float2bfloat16((xv.w - mu) * rstd * wv.w + bv.w);
  *(uint2*)&xout[row * D_ + lane * 4] = *(uint2*)tmp;
}

// ---------------- MFMA GEMM (reg-prefetch, 256 thr; used for uw) ----------------
__global__ __launch_bounds__(256) void mgemm(const bf16* __restrict__ Ab,
    const bf16* __restrict__ Wt, const float* __restrict__ bias,
    const float* __restrict__ Res, float* __restrict__ Cf, bf16* __restrict__ Cb,
    int K, int N, int flags)
{
  __shared__ short As[64][40];
  __shared__ short Bs[64][40];
  int t = threadIdx.x;
  int m0 = blockIdx.y * 64, n0 = blockIdx.x * 64;
  int w = t >> 6, lane = t & 63;
  int srow = t >> 2, sseg = t & 3;
  f32x4 acc[4] = {{0.f,0.f,0.f,0.f},{0.f,0.f,0.f,0.f},{0.f,0.f,0.f,0.f},{0.f,0.f,0.f,0.f}};
  int mf = w * 16 + (lane & 15);
  int kf = (lane >> 4) * 8;
  const bf16* pA = Ab + (size_t)(m0 + srow) * K + sseg * 8;
  const bf16* pB = Wt + (size_t)(n0 + srow) * K + sseg * 8;
  uint4 ra = *(const uint4*)pA;
  uint4 rb = *(const uint4*)pB;
  for (int k0 = 0; k0 < K; k0 += 32) {
    *(uint4*)&As[srow][sseg * 8] = ra;
    *(uint4*)&Bs[srow][sseg * 8] = rb;
    __syncthreads();
    if (k0 + 32 < K) {
      ra = *(const uint4*)(pA + k0 + 32);
      rb = *(const uint4*)(pB + k0 + 32);
    }
    short8 a = *(short8*)&As[mf][kf];
    #pragma unroll
    for (int nt = 0; nt < 4; ++nt) {
      short8 bfr = *(short8*)&Bs[nt * 16 + (lane & 15)][kf];
      acc[nt] = __builtin_amdgcn_mfma_f32_16x16x32_bf16(a, bfr, acc[nt], 0, 0, 0);
    }
    __syncthreads();
  }
  int row0 = m0 + w * 16 + (lane >> 4) * 4;
  #pragma unroll
  for (int nt = 0; nt < 4; ++nt) {
    int col = n0 + nt * 16 + (lane & 15);
    float bs = bias[col];
    #pragma unroll
    for (int r = 0; r < 4; ++r) {
      float v = acc[nt][r] + bs;
      if (flags & 1) v = 0.5f * v * (1.0f + erff(v * 0.70710678118654752f));
      if (flags & 2) v += Res[(size_t)(row0 + r) * N + col];
      if (flags & 8) Cf[(size_t)(row0 + r) * N + col] = v;
      if (flags & 4) Cb[(size_t)(row0 + r) * N + col] = __float2bfloat16(v);
    }
  }
}

// ---------------- MFMA GEMM, 512 threads / 8 waves per 64x64 tile (wo/dw/fin) ----------------
__global__ __launch_bounds__(512) void mgemm512(const bf16* __restrict__ Ab,
    const bf16* __restrict__ Wt, const float* __restrict__ bias,
    const float* __restrict__ Res, float* __restrict__ Cf, bf16* __restrict__ Cb,
    int K, int N, int flags)
{
  __shared__ short As[64][40];
  __shared__ short Bs[64][40];
  int t = threadIdx.x;
  int m0 = blockIdx.y * 64, n0 = blockIdx.x * 64;
  int w = t >> 6, lane = t & 63;
  int l16 = lane & 15, quad = lane >> 4;
  int s = t & 255;
  int srow = s >> 2, sseg = s & 3;
  bool isA = (t < 256);
  short (*S)[40] = isA ? As : Bs;
  const bf16* pS = (isA ? Ab + (size_t)(m0 + srow) * K
                        : Wt + (size_t)(n0 + srow) * K) + sseg * 8;
  uint4 ra = *(const uint4*)pS;
  f32x4 acc[2] = {{0.f,0.f,0.f,0.f},{0.f,0.f,0.f,0.f}};
  int mf = (w & 3) * 16 + l16;
  int kf = quad * 8;
  int ntb = (w >> 2) * 2;
  for (int k0 = 0; k0 < K; k0 += 32) {
    *(uint4*)&S[srow][sseg * 8] = ra;
    __syncthreads();
    if (k0 + 32 < K) ra = *(const uint4*)(pS + k0 + 32);
    short8 a = *(short8*)&As[mf][kf];
    #pragma unroll
    for (int i = 0; i < 2; ++i) {
      short8 bfr = *(short8*)&Bs[(ntb + i) * 16 + l16][kf];
      acc[i] = __builtin_amdgcn_mfma_f32_16x16x32_bf16(a, bfr, acc[i], 0, 0, 0);
    }
    __syncthreads();
  }
  int row0 = m0 + (w & 3) * 16 + quad * 4;
  #pragma unroll
  for (int i = 0; i < 2; ++i) {
    int col = n0 + (ntb + i) * 16 + l16;
    float bs = bias[col];
    #pragma unroll
    for (int r = 0; r < 4; ++r) {
      float v = acc[i][r] + bs;
      if (flags & 1) v = 0.5f * v * (1.0f + erff(v * 0.70710678118654752f));
      if (flags & 2) v += Res[(size_t)(row0 + r) * N + col];
      if (flags & 8) Cf[(size_t)(row0 + r) * N + col] = v;
      if (flags & 4) Cb[(size_t)(row0 + r) * N + col] = __float2bfloat16(v);
    }
  }
}

// ---------------- fused QKV MFMA GEMM (reg-prefetch, unchanged) ----------------
__global__ __launch_bounds__(256) void mgemm_qkv(const bf16* __restrict__ Ab,
    const bf16* __restrict__ Wt, const float* __restrict__ bq,
    const float* __restrict__ bk, const float* __restrict__ bv,
    bf16* __restrict__ qo, bf16* __restrict__ ko, bf16* __restrict__ vo)
{
  __shared__ short As[64][40];
  __shared__ short Bs[64][40];
  int t = threadIdx.x;
  int m0 = blockIdx.y * 64, n0g = blockIdx.x * 64;
  int w = t >> 6, lane = t & 63;
  int srow = t >> 2, sseg = t & 3;
  f32x4 acc[4] = {{0.f,0.f,0.f,0.f},{0.f,0.f,0.f,0.f},{0.f,0.f,0.f,0.f},{0.f,0.f,0.f,0.f}};
  int mf = w * 16 + (lane & 15);
  int kf = (lane >> 4) * 8;
  const bf16* pA = Ab + (size_t)(m0 + srow) * 256 + sseg * 8;
  const bf16* pB = Wt + (size_t)(n0g + srow) * 256 + sseg * 8;
  uint4 ra = *(const uint4*)pA;
  uint4 rb = *(const uint4*)pB;
  for (int k0 = 0; k0 < 256; k0 += 32) {
    *(uint4*)&As[srow][sseg * 8] = ra;
    *(uint4*)&Bs[srow][sseg * 8] = rb;
    __syncthreads();
    if (k0 + 32 < 256) {
      ra = *(const uint4*)(pA + k0 + 32);
      rb = *(const uint4*)(pB + k0 + 32);
    }
    short8 a = *(short8*)&As[mf][kf];
    #pragma unroll
    for (int nt = 0; nt < 4; ++nt) {
      short8 bfr = *(short8*)&Bs[nt * 16 + (lane & 15)][kf];
      acc[nt] = __builtin_amdgcn_mfma_f32_16x16x32_bf16(a, bfr, acc[nt], 0, 0, 0);
    }
    __syncthreads();
  }
  int seg = n0g >> 8;
  const float* bb = (seg == 0 ? bq : (seg == 1 ? bk : bv));
  bf16* dst = (seg == 0 ? qo : (seg == 1 ? ko : vo));
  int row0 = m0 + w * 16 + (lane >> 4) * 4;
  #pragma unroll
  for (int nt = 0; nt < 4; ++nt) {
    int col = (n0g & 255) + nt * 16 + (lane & 15);
    float bs = bb[col];
    #pragma unroll
    for (int r = 0; r < 4; ++r)
      dst[(size_t)(row0 + r) * 256 + col] = __float2bfloat16(acc[nt][r] + bs);
  }
}

// ---------------- MFMA flash attention with K/V register prefetch ----------------
__global__ __launch_bounds__(256) void k_flash(const bf16* __restrict__ q,
    const bf16* __restrict__ k, const bf16* __restrict__ v, bf16* __restrict__ o)
{
  int qt = blockIdx.x, h = blockIdx.y, b = blockIdx.z;
  int t = threadIdx.x;
  int w = t >> 6, lane = t & 63;
  int quad = lane >> 4, l16 = lane & 15;
  __shared__ short Ks[64][40];
  __shared__ short Vt[32][76];
  __shared__ short Pl[4][16][72];
  short8 a_q = *(const short8*)&q[((size_t)(b * M_) + qt * 64 + w * 16 + l16) * D_ + h * 32 + quad * 8];
  f32x4 o_acc[2] = {{0.f,0.f,0.f,0.f},{0.f,0.f,0.f,0.f}};
  float l_acc[4] = {0.f, 0.f, 0.f, 0.f};
  int skey = t >> 2, sseg = t & 3;
  const float scale = 0.17677669529663687f;
  const bf16* pk = &k[((size_t)(b * M_) + skey) * D_ + h * 32 + sseg * 8];
  const bf16* pv = &v[((size_t)(b * M_) + skey) * D_ + h * 32 + sseg * 8];
  short8 rk = *(const short8*)pk;    // kt = 0 staged in regs
  short8 rv = *(const short8*)pv;
  for (int kt = 0; kt < 16; ++kt) {
    *(short8*)&Ks[skey][sseg * 8] = rk;
    #pragma unroll
    for (int i = 0; i < 8; ++i) Vt[sseg * 8 + i][skey] = rv[i];
    __syncthreads();
    if (kt < 15) {                    // prefetch kt+1 under compute
      rk = *(const short8*)(pk + (size_t)(kt + 1) * 64 * D_);
      rv = *(const short8*)(pv + (size_t)(kt + 1) * 64 * D_);
    }
    #pragma unroll
    for (int st = 0; st < 4; ++st) {
      short8 bf = *(short8*)&Ks[st * 16 + l16][quad * 8];
      f32x4 s4 = __builtin_amdgcn_mfma_f32_16x16x32_bf16(a_q, bf, (f32x4){0.f,0.f,0.f,0.f}, 0, 0, 0);
      #pragma unroll
      for (int r = 0; r < 4; ++r) {
        float p = __expf(s4[r] * scale);
        l_acc[r] += p;
        bf16 hb = __float2bfloat16(p);
        Pl[w][quad * 4 + r][st * 16 + l16] = *reinterpret_cast<short*>(&hb);
      }
    }
    asm volatile("s_waitcnt lgkmcnt(0)" ::: "memory");
    #pragma unroll
    for (int kh = 0; kh < 2; ++kh) {
      short8 a_p = *(short8*)&Pl[w][l16][kh * 32 + quad * 8];
      #pragma unroll
      for (int nt = 0; nt < 2; ++nt) {
        short8 b_v = *(short8*)&Vt[nt * 16 + l16][kh * 32 + quad * 8];
        o_acc[nt] = __builtin_amdgcn_mfma_f32_16x16x32_bf16(a_p, b_v, o_acc[nt], 0, 0, 0);
      }
    }
    __syncthreads();
  }
  #pragma unroll
  for (int r = 0; r < 4; ++r) {
    float lv = l_acc[r];
    lv += __shfl_xor(lv, 1, 64);
    lv += __shfl_xor(lv, 2, 64);
    lv += __shfl_xor(lv, 4, 64);
    lv += __shfl_xor(lv, 8, 64);
    l_acc[r] = 1.0f / lv;
  }
  #pragma unroll
  for (int nt = 0; nt < 2; ++nt)
    #pragma unroll
    for (int r = 0; r < 4; ++r)
      o[((size_t)(b * M_) + qt * 64 + w * 16 + quad * 4 + r) * D_ + h * 32 + nt * 16 + l16] =
          __float2bfloat16(o_acc[nt][r] * l_acc[r]);
}

// ---------------- fused s head: 8 waves, both triangle tiles in parallel, direct out ----------------
// waves 0-3 compute Sa = tile(it-rows, jt-cols); waves 4-7 compute Sb = tile(jt-rows, it-cols).
// Then symmetrize from LDS: out[it,jt] = 0.5(Sa + Sb^T); out[jt,it] = 0.5(Sb + Sa^T).
__global__ __launch_bounds__(512) void k_shead_f(const bf16* __restrict__ q3,
    const bf16* __restrict__ k3, const float* __restrict__ snw, const float* __restrict__ snb,
    const float* __restrict__ sfw, const float* __restrict__ sfb, float* __restrict__ outs)
{
  int p = blockIdx.x, b = blockIdx.z;
  int it = 0;
  while ((it + 1) * (it + 2) / 2 <= p) ++it;
  int jt = p - it * (it + 1) / 2;
  int t = threadIdx.x;
  int half = t >> 8;          // 0 -> Sa, 1 -> Sb
  int tl = t & 255;
  int w = tl >> 6, lane = tl & 63;
  int quad = lane >> 4, l16 = lane & 15;
  __shared__ float Sa[64][65], Sb[64][65];
  const float scale = 0.17677669529663687f;
  float wsn[H_], bsn[H_], wsf[H_];
  #pragma unroll
  for (int h = 0; h < H_; ++h) { wsn[h] = snw[h]; bsn[h] = snb[h]; wsf[h] = sfw[h]; }
  float bias0 = sfb[0];
  int rt = half ? jt : it;    // q-row tile
  int ct = half ? it : jt;    // k-col tile  (diag: both halves compute identical values)
  float (*S)[65] = half ? Sb : Sa;
  short8 aqs[H_];
  #pragma unroll
  for (int h = 0; h < H_; ++h)
    aqs[h] = *(const short8*)&q3[((size_t)(b * M_) + rt * 64 + w * 16 + l16) * D_ + h * 32 + quad * 8];
  #pragma unroll
  for (int cf = 0; cf < 4; ++cf) {
    f32x4 s4[H_];
    #pragma unroll
    for (int h = 0; h < H_; ++h) {
      short8 bk = *(const short8*)&k3[((size_t)(b * M_) + ct * 64 + cf * 16 + l16) * D_ + h * 32 + quad * 8];
      s4[h] = __builtin_amdgcn_mfma_f32_16x16x32_bf16(aqs[h], bk, (f32x4){0.f,0.f,0.f,0.f}, 0, 0, 0);
    }
    #pragma unroll
    for (int r = 0; r < 4; ++r) {
      float d8[H_], ssum = 0.f, ssq = 0.f;
      #pragma unroll
      for (int h = 0; h < H_; ++h) {
        float s = s4[h][r] * scale;
        d8[h] = s; ssum += s; ssq += s * s;
      }
      float mu = ssum * 0.125f;
      float var = ssq * 0.125f - mu * mu;
      float rstd = rsqrtf(var + 1e-5f);
      float val = bias0;
      #pragma unroll
      for (int h = 0; h < H_; ++h)
        val += ((d8[h] - mu) * rstd * wsn[h] + bsn[h]) * wsf[h];
      S[w * 16 + quad * 4 + r][cf * 16 + l16] = val;
    }
  }
  __syncthreads();
  bool diag = (it == jt);
  int i = tl >> 2, j0 = (tl & 3) * 16;
  if (half == 0) {
    #pragma unroll
    for (int jj = 0; jj < 16; ++jj) {
      int j = j0 + jj;
      outs[((size_t)(b * M_) + it * 64 + i) * M_ + jt * 64 + j] = 0.5f * (Sa[i][j] + Sb[j][i]);
    }
  } else if (!diag) {
    #pragma unroll
    for (int ii = 0; ii < 16; ++ii) {
      int i2 = j0 + ii;
      outs[((size_t)(b * M_) + jt * 64 + i) * M_ + it * 64 + i2] = 0.5f * (Sb[i][i2] + Sa[i2][i]);
    }
  }
}

extern "C" void kernel_launch(void* const* d_in, const int* in_sizes, int n_in,
                              void* d_out, int out_size, void* d_ws, size_t ws_size,
                              hipStream_t stream)
{
  const float* X    = (const float*)d_in[0];
  const float* fW   = (const float*)d_in[2];
  const float* fb   = (const float*)d_in[3];
  const float* cW   = (const float*)d_in[4];
  const float* cb   = (const float*)d_in[5];
  const float* Wq   = (const float*)d_in[6];
  const float* bq   = (const float*)d_in[7];
  const float* Wk   = (const float*)d_in[8];
  const float* bk   = (const float*)d_in[9];
  const float* Wv   = (const float*)d_in[10];
  const float* bv   = (const float*)d_in[11];
  const float* Wo   = (const float*)d_in[12];
  const float* bo   = (const float*)d_in[13];
  const float* ln1w = (const float*)d_in[14];
  const float* ln1b = (const float*)d_in[15];
  const float* ln2w = (const float*)d_in[16];
  const float* ln2b = (const float*)d_in[17];
  const float* lnfw = (const float*)d_in[18];
  const float* lnfb = (const float*)d_in[19];
  const float* uw   = (const float*)d_in[20];
  const float* ub   = (const float*)d_in[21];
  const float* dw   = (const float*)d_in[22];
  const float* db   = (const float*)d_in[23];
  const float* finw = (const float*)d_in[24];
  const float* finb = (const float*)d_in[25];
  const float* snw  = (const float*)d_in[26];
  const float* snb  = (const float*)d_in[27];
  const float* sfw  = (const float*)d_in[28];
  const float* sfb  = (const float*)d_in[29];

  char* base = (char*)d_ws;
  const size_t MiB = 1024 * 1024;
  bf16* q_b   = (bf16*)(base + 0 * MiB);              // layer-3 q lives until s head
  bf16* k_b   = (bf16*)(base + 2 * MiB);              // layer-3 k lives until s head
  bf16* wqkvt = (bf16*)(base + 4 * MiB);              // 1.5 MiB
  bf16* wot   = (bf16*)(base + 5 * MiB + 512 * 1024); // 512 KiB
  bf16* uwt   = (bf16*)(base + 6 * MiB);              // 2 MiB
  bf16* dwt   = (bf16*)(base + 8 * MiB);              // 2 MiB
  bf16* fwt   = (bf16*)(base + 10 * MiB);             // 32 KiB
  float* x    = (float*)(base + 10 * MiB + 512 * 1024); // 4 MiB
  char* SR    = base + 14 * MiB + 512 * 1024;
  bf16* xn_b  = (bf16*)(SR + 0 * MiB);
  bf16* v_b   = (bf16*)(SR + 2 * MiB);
  bf16* att_b = (bf16*)(SR + 4 * MiB);
  bf16* h1_b  = (bf16*)(SR + 6 * MiB);                // 8 MiB
  float* outx = (float*)d_out;
  float* outs = outx + (size_t)BM_TOT * 64;

  dim3 blk(256);
  dim3 blk512(512);
  wconv_all<<<dim3(772), blk, 0, stream>>>(Wq, Wk, Wv, Wo, uw, dw, finw,
                                           wqkvt, wot, uwt, dwt, fwt);
  k_embed<<<dim3(BM_TOT / 4), blk, 0, stream>>>(X, fW, fb, cW, cb, x);
  for (int l = 0; l < L_; ++l) {
    k_ln<<<dim3(BM_TOT / 4), blk, 0, stream>>>(x, ln1w + l * D_, ln1b + l * D_, xn_b);
    mgemm_qkv<<<dim3(12, 64), blk, 0, stream>>>(xn_b, wqkvt + (size_t)l * 196608,
                                                bq + l * D_, bk + l * D_, bv + l * D_,
                                                q_b, k_b, v_b);
    k_flash<<<dim3(16, H_, B_), blk, 0, stream>>>(q_b, k_b, v_b, att_b);
    mgemm512<<<dim3(4, 64), blk512, 0, stream>>>(att_b, wot + (size_t)l * 65536, bo + l * D_,
                                                 x, x, nullptr, 256, 256, 2 | 8);
    k_ln<<<dim3(BM_TOT / 4), blk, 0, stream>>>(x, ln2w + l * D_, ln2b + l * D_, xn_b);
    mgemm<<<dim3(16, 64), blk, 0, stream>>>(xn_b, uwt + (size_t)l * 262144, ub + l * DFF_,
                                            nullptr, nullptr, h1_b, 256, 1024, 1 | 4);
    mgemm512<<<dim3(4, 64), blk512, 0, stream>>>(h1_b, dwt + (size_t)l * 262144, db + l * D_,
                                                 x, x, nullptr, 1024, 256, 2 | 8);
  }
  k_ln<<<dim3(BM_TOT / 4), blk, 0, stream>>>(x, lnfw, lnfb, xn_b);
  mgemm512<<<dim3(1, 64), blk512, 0, stream>>>(xn_b, fwt, finb, nullptr, outx, nullptr, 256, 64, 8);
  // layer-3 q/k still live in q_b/k_b
  k_shead_f<<<dim3(136, 1, B_), blk512, 0, stream>>>(q_b, k_b, snw, snb, sfw, sfb, outs);
}

// Round 8
// 419.060 us; speedup vs baseline: 1.1362x; 1.0428x over previous
//
#include <hip/hip_runtime.h>
#include <hip/hip_bf16.h>
#include <math.h>

#define B_ 4
#define M_ 1024
#define NIN 70
#define D_ 256
#define H_ 8
#define L_ 4
#define DFF_ 1024
#define BM_TOT 4096

typedef __hip_bfloat16 bf16;
typedef short short8 __attribute__((ext_vector_type(8)));
typedef float f32x4 __attribute__((ext_vector_type(4)));

// ---------------- single-launch weight convert+transpose ----------------
__global__ __launch_bounds__(256) void wconv_all(
    const float* __restrict__ Wq, const float* __restrict__ Wk, const float* __restrict__ Wv,
    const float* __restrict__ Wo, const float* __restrict__ uw, const float* __restrict__ dw,
    const float* __restrict__ finw,
    bf16* __restrict__ wqkvt, bf16* __restrict__ wot, bf16* __restrict__ uwt,
    bf16* __restrict__ dwt, bf16* __restrict__ fwt)
{
  __shared__ float T[64][65];
  int idx = blockIdx.x;
  const float* src; bf16* dst; int K, N, k0, n0, rbase, S;
  if (idx < 192) {            // Wq/Wk/Wv -> wqkvt[l][m*256 + n][k]
    int m = idx >> 6; int r = idx & 63; int l = r >> 4; int tt = r & 15;
    int kt = tt >> 2, nt = tt & 3;
    src = (m == 0 ? Wq : (m == 1 ? Wk : Wv)) + (size_t)l * 65536;
    K = 256; N = 256; k0 = kt * 64; n0 = nt * 64;
    dst = wqkvt + (size_t)l * 196608; rbase = m * 256 + nt * 64; S = 256;
  } else if (idx < 256) {     // Wo
    int r = idx - 192; int l = r >> 4; int tt = r & 15; int kt = tt >> 2, nt = tt & 3;
    src = Wo + (size_t)l * 65536; K = 256; N = 256; k0 = kt * 64; n0 = nt * 64;
    dst = wot + (size_t)l * 65536; rbase = nt * 64; S = 256;
  } else if (idx < 512) {     // uw (256 x 1024)
    int r = idx - 256; int l = r >> 6; int tt = r & 63; int kt = tt >> 4, nt = tt & 15;
    src = uw + (size_t)l * 262144; K = 256; N = 1024; k0 = kt * 64; n0 = nt * 64;
    dst = uwt + (size_t)l * 262144; rbase = nt * 64; S = 256;
  } else if (idx < 768) {     // dw (1024 x 256)
    int r = idx - 512; int l = r >> 6; int tt = r & 63; int kt = tt >> 2, nt = tt & 3;
    src = dw + (size_t)l * 262144; K = 1024; N = 256; k0 = kt * 64; n0 = nt * 64;
    dst = dwt + (size_t)l * 262144; rbase = nt * 64; S = 1024;
  } else {                    // finw (256 x 64)
    int kt = idx - 768;
    src = finw; K = 256; N = 64; k0 = kt * 64; n0 = 0;
    dst = fwt; rbase = 0; S = 256;
  }
  int t = threadIdx.x;
  int kl = t >> 2, ns = (t & 3) * 16;
  #pragma unroll
  for (int i = 0; i < 16; i += 4)
    *(float4*)&T[kl][ns + i] = *(const float4*)&src[(size_t)(k0 + kl) * N + n0 + ns + i];
  __syncthreads();
  int nl = t >> 2, ks = (t & 3) * 16;
  __align__(16) bf16 tmp[16];
  #pragma unroll
  for (int i = 0; i < 16; ++i) tmp[i] = __float2bfloat16(T[ks + i][nl]);
  *(uint4*)&dst[(size_t)(rbase + nl) * S + k0 + ks] = *(uint4*)&tmp[0];
  *(uint4*)&dst[(size_t)(rbase + nl) * S + k0 + ks + 8] = *(uint4*)&tmp[8];
}

// ---------------- embedding: 4 rows/block ----------------
__global__ __launch_bounds__(256) void k_embed(const float* __restrict__ X,
    const float* __restrict__ fW, const float* __restrict__ fb,
    const float* __restrict__ cW, const float* __restrict__ cb,
    float* __restrict__ x)
{
  int bm0 = blockIdx.x * 4;
  int d = threadIdx.x;
  __shared__ float xr[4][NIN];
  for (int i = d; i < 4 * NIN; i += 256)
    xr[i / NIN][i % NIN] = X[(size_t)(bm0 + i / NIN) * NIN + i % NIN];
  __syncthreads();
  int f = d & 127;
  float fw0 = fW[f * 3 + 0], fw1 = fW[f * 3 + 1], fw2 = fW[f * 3 + 2], fbv = fb[f];
  float cbv = cb[d];
  float acc[4];
  #pragma unroll
  for (int r = 0; r < 4; ++r) {
    float proj = xr[r][0] * fw0 + xr[r][1] * fw1 + xr[r][2] * fw2 + fbv;
    acc[r] = (d < 128 ? cosf(proj) : sinf(proj)) * 0.17677669529663687f + cbv;
  }
  #pragma unroll 8
  for (int c = 0; c < 64; ++c) {
    float cw = cW[c * D_ + d];
    #pragma unroll
    for (int r = 0; r < 4; ++r) acc[r] += xr[r][6 + c] * cw;
  }
  #pragma unroll
  for (int r = 0; r < 4; ++r)
    x[(size_t)(bm0 + r) * D_ + d] = acc[r];
}

// ---------------- layernorm: fp32 in -> bf16 out ----------------
__global__ __launch_bounds__(256) void k_ln(const float* __restrict__ xin,
    const float* __restrict__ w, const float* __restrict__ b, bf16* __restrict__ xout)
{
  int wave = threadIdx.x >> 6;
  int lane = threadIdx.x & 63;
  int row = blockIdx.x * 4 + wave;
  float4 xv = *(const float4*)&xin[row * D_ + lane * 4];
  float s = xv.x + xv.y + xv.z + xv.w;
  float q = xv.x * xv.x + xv.y * xv.y + xv.z * xv.z + xv.w * xv.w;
  #pragma unroll
  for (int off = 32; off; off >>= 1) {
    s += __shfl_xor(s, off, 64);
    q += __shfl_xor(q, off, 64);
  }
  float mu = s * (1.0f / D_);
  float var = q * (1.0f / D_) - mu * mu;
  float rstd = rsqrtf(var + 1e-5f);
  float4 wv = *(const float4*)&w[lane * 4];
  float4 bv = *(const float4*)&b[lane * 4];
  __align__(8) bf16 tmp[4];
  tmp[0] = __float2bfloat16((xv.x - mu) * rstd * wv.x + bv.x);
  tmp[1] = __float2bfloat16((xv.y - mu) * rstd * wv.y + bv.y);
  tmp[2] = __float2bfloat16((xv.z - mu) * rstd * wv.z + bv.z);
  tmp[3] = __float2bfloat16((xv.w - mu) * rstd * wv.w + bv.w);
  *(uint2*)&xout[row * D_ + lane * 4] = *(uint2*)tmp;
}

// ---------------- MFMA GEMM (reg-prefetch, BK=64; used for uw) ----------------
__global__ __launch_bounds__(256) void mgemm(const bf16* __restrict__ Ab,
    const bf16* __restrict__ Wt, const float* __restrict__ bias,
    const float* __restrict__ Res, float* __restrict__ Cf, bf16* __restrict__ Cb,
    int K, int N, int flags)
{
  __shared__ short As[64][72];
  __shared__ short Bs[64][72];
  int t = threadIdx.x;
  int m0 = blockIdx.y * 64, n0 = blockIdx.x * 64;
  int w = t >> 6, lane = t & 63;
  int srow = t >> 2, sseg = (t & 3) * 16;
  f32x4 acc[4] = {{0.f,0.f,0.f,0.f},{0.f,0.f,0.f,0.f},{0.f,0.f,0.f,0.f},{0.f,0.f,0.f,0.f}};
  int mf = w * 16 + (lane & 15);
  int kf = (lane >> 4) * 8;
  const bf16* pA = Ab + (size_t)(m0 + srow) * K + sseg;
  const bf16* pB = Wt + (size_t)(n0 + srow) * K + sseg;
  uint4 ra0 = *(const uint4*)pA, ra1 = *(const uint4*)(pA + 8);
  uint4 rb0 = *(const uint4*)pB, rb1 = *(const uint4*)(pB + 8);
  for (int k0 = 0; k0 < K; k0 += 64) {
    *(uint4*)&As[srow][sseg] = ra0;
    *(uint4*)&As[srow][sseg + 8] = ra1;
    *(uint4*)&Bs[srow][sseg] = rb0;
    *(uint4*)&Bs[srow][sseg + 8] = rb1;
    __syncthreads();
    if (k0 + 64 < K) {
      ra0 = *(const uint4*)(pA + k0 + 64);
      ra1 = *(const uint4*)(pA + k0 + 72);
      rb0 = *(const uint4*)(pB + k0 + 64);
      rb1 = *(const uint4*)(pB + k0 + 72);
    }
    #pragma unroll
    for (int kk = 0; kk < 64; kk += 32) {
      short8 a = *(short8*)&As[mf][kk + kf];
      #pragma unroll
      for (int nt = 0; nt < 4; ++nt) {
        short8 bfr = *(short8*)&Bs[nt * 16 + (lane & 15)][kk + kf];
        acc[nt] = __builtin_amdgcn_mfma_f32_16x16x32_bf16(a, bfr, acc[nt], 0, 0, 0);
      }
    }
    __syncthreads();
  }
  int row0 = m0 + w * 16 + (lane >> 4) * 4;
  #pragma unroll
  for (int nt = 0; nt < 4; ++nt) {
    int col = n0 + nt * 16 + (lane & 15);
    float bs = bias[col];
    #pragma unroll
    for (int r = 0; r < 4; ++r) {
      float v = acc[nt][r] + bs;
      if (flags & 1) v = 0.5f * v * (1.0f + erff(v * 0.70710678118654752f));
      if (flags & 2) v += Res[(size_t)(row0 + r) * N + col];
      if (flags & 8) Cf[(size_t)(row0 + r) * N + col] = v;
      if (flags & 4) Cb[(size_t)(row0 + r) * N + col] = __float2bfloat16(v);
    }
  }
}

// ---------------- MFMA GEMM, 512 thr / 8 waves, BK=64 (wo/dw/fin) ----------------
__global__ __launch_bounds__(512) void mgemm512(const bf16* __restrict__ Ab,
    const bf16* __restrict__ Wt, const float* __restrict__ bias,
    const float* __restrict__ Res, float* __restrict__ Cf, bf16* __restrict__ Cb,
    int K, int N, int flags)
{
  __shared__ short As[64][72];
  __shared__ short Bs[64][72];
  int t = threadIdx.x;
  int m0 = blockIdx.y * 64, n0 = blockIdx.x * 64;
  int w = t >> 6, lane = t & 63;
  int l16 = lane & 15, quad = lane >> 4;
  int s = t & 255;
  int srow = s >> 2, sseg = (s & 3) * 16;
  bool isA = (t < 256);
  short (*S)[72] = isA ? As : Bs;
  const bf16* pS = (isA ? Ab + (size_t)(m0 + srow) * K
                        : Wt + (size_t)(n0 + srow) * K) + sseg;
  uint4 ra0 = *(const uint4*)pS, ra1 = *(const uint4*)(pS + 8);
  f32x4 acc[2] = {{0.f,0.f,0.f,0.f},{0.f,0.f,0.f,0.f}};
  int mf = (w & 3) * 16 + l16;
  int kf = quad * 8;
  int ntb = (w >> 2) * 2;
  for (int k0 = 0; k0 < K; k0 += 64) {
    *(uint4*)&S[srow][sseg] = ra0;
    *(uint4*)&S[srow][sseg + 8] = ra1;
    __syncthreads();
    if (k0 + 64 < K) {
      ra0 = *(const uint4*)(pS + k0 + 64);
      ra1 = *(const uint4*)(pS + k0 + 72);
    }
    #pragma unroll
    for (int kk = 0; kk < 64; kk += 32) {
      short8 a = *(short8*)&As[mf][kk + kf];
      #pragma unroll
      for (int i = 0; i < 2; ++i) {
        short8 bfr = *(short8*)&Bs[(ntb + i) * 16 + l16][kk + kf];
        acc[i] = __builtin_amdgcn_mfma_f32_16x16x32_bf16(a, bfr, acc[i], 0, 0, 0);
      }
    }
    __syncthreads();
  }
  int row0 = m0 + (w & 3) * 16 + quad * 4;
  #pragma unroll
  for (int i = 0; i < 2; ++i) {
    int col = n0 + (ntb + i) * 16 + l16;
    float bs = bias[col];
    #pragma unroll
    for (int r = 0; r < 4; ++r) {
      float v = acc[i][r] + bs;
      if (flags & 1) v = 0.5f * v * (1.0f + erff(v * 0.70710678118654752f));
      if (flags & 2) v += Res[(size_t)(row0 + r) * N + col];
      if (flags & 8) Cf[(size_t)(row0 + r) * N + col] = v;
      if (flags & 4) Cb[(size_t)(row0 + r) * N + col] = __float2bfloat16(v);
    }
  }
}

// ---------------- fused QKV MFMA GEMM (reg-prefetch, BK=64) ----------------
__global__ __launch_bounds__(256) void mgemm_qkv(const bf16* __restrict__ Ab,
    const bf16* __restrict__ Wt, const float* __restrict__ bq,
    const float* __restrict__ bk, const float* __restrict__ bv,
    bf16* __restrict__ qo, bf16* __restrict__ ko, bf16* __restrict__ vo)
{
  __shared__ short As[64][72];
  __shared__ short Bs[64][72];
  int t = threadIdx.x;
  int m0 = blockIdx.y * 64, n0g = blockIdx.x * 64;
  int w = t >> 6, lane = t & 63;
  int srow = t >> 2, sseg = (t & 3) * 16;
  f32x4 acc[4] = {{0.f,0.f,0.f,0.f},{0.f,0.f,0.f,0.f},{0.f,0.f,0.f,0.f},{0.f,0.f,0.f,0.f}};
  int mf = w * 16 + (lane & 15);
  int kf = (lane >> 4) * 8;
  const bf16* pA = Ab + (size_t)(m0 + srow) * 256 + sseg;
  const bf16* pB = Wt + (size_t)(n0g + srow) * 256 + sseg;
  uint4 ra0 = *(const uint4*)pA, ra1 = *(const uint4*)(pA + 8);
  uint4 rb0 = *(const uint4*)pB, rb1 = *(const uint4*)(pB + 8);
  for (int k0 = 0; k0 < 256; k0 += 64) {
    *(uint4*)&As[srow][sseg] = ra0;
    *(uint4*)&As[srow][sseg + 8] = ra1;
    *(uint4*)&Bs[srow][sseg] = rb0;
    *(uint4*)&Bs[srow][sseg + 8] = rb1;
    __syncthreads();
    if (k0 + 64 < 256) {
      ra0 = *(const uint4*)(pA + k0 + 64);
      ra1 = *(const uint4*)(pA + k0 + 72);
      rb0 = *(const uint4*)(pB + k0 + 64);
      rb1 = *(const uint4*)(pB + k0 + 72);
    }
    #pragma unroll
    for (int kk = 0; kk < 64; kk += 32) {
      short8 a = *(short8*)&As[mf][kk + kf];
      #pragma unroll
      for (int nt = 0; nt < 4; ++nt) {
        short8 bfr = *(short8*)&Bs[nt * 16 + (lane & 15)][kk + kf];
        acc[nt] = __builtin_amdgcn_mfma_f32_16x16x32_bf16(a, bfr, acc[nt], 0, 0, 0);
      }
    }
    __syncthreads();
  }
  int seg = n0g >> 8;
  const float* bb = (seg == 0 ? bq : (seg == 1 ? bk : bv));
  bf16* dst = (seg == 0 ? qo : (seg == 1 ? ko : vo));
  int row0 = m0 + w * 16 + (lane >> 4) * 4;
  #pragma unroll
  for (int nt = 0; nt < 4; ++nt) {
    int col = (n0g & 255) + nt * 16 + (lane & 15);
    float bs = bb[col];
    #pragma unroll
    for (int r = 0; r < 4; ++r)
      dst[(size_t)(row0 + r) * 256 + col] = __float2bfloat16(acc[nt][r] + bs);
  }
}

// ---------------- MFMA flash attention with K/V register prefetch (unchanged) ----------------
__global__ __launch_bounds__(256) void k_flash(const bf16* __restrict__ q,
    const bf16* __restrict__ k, const bf16* __restrict__ v, bf16* __restrict__ o)
{
  int qt = blockIdx.x, h = blockIdx.y, b = blockIdx.z;
  int t = threadIdx.x;
  int w = t >> 6, lane = t & 63;
  int quad = lane >> 4, l16 = lane & 15;
  __shared__ short Ks[64][40];
  __shared__ short Vt[32][76];
  __shared__ short Pl[4][16][72];
  short8 a_q = *(const short8*)&q[((size_t)(b * M_) + qt * 64 + w * 16 + l16) * D_ + h * 32 + quad * 8];
  f32x4 o_acc[2] = {{0.f,0.f,0.f,0.f},{0.f,0.f,0.f,0.f}};
  float l_acc[4] = {0.f, 0.f, 0.f, 0.f};
  int skey = t >> 2, sseg = t & 3;
  const float scale = 0.17677669529663687f;
  const bf16* pk = &k[((size_t)(b * M_) + skey) * D_ + h * 32 + sseg * 8];
  const bf16* pv = &v[((size_t)(b * M_) + skey) * D_ + h * 32 + sseg * 8];
  short8 rk = *(const short8*)pk;    // kt = 0 staged in regs
  short8 rv = *(const short8*)pv;
  for (int kt = 0; kt < 16; ++kt) {
    *(short8*)&Ks[skey][sseg * 8] = rk;
    #pragma unroll
    for (int i = 0; i < 8; ++i) Vt[sseg * 8 + i][skey] = rv[i];
    __syncthreads();
    if (kt < 15) {                    // prefetch kt+1 under compute
      rk = *(const short8*)(pk + (size_t)(kt + 1) * 64 * D_);
      rv = *(const short8*)(pv + (size_t)(kt + 1) * 64 * D_);
    }
    #pragma unroll
    for (int st = 0; st < 4; ++st) {
      short8 bf = *(short8*)&Ks[st * 16 + l16][quad * 8];
      f32x4 s4 = __builtin_amdgcn_mfma_f32_16x16x32_bf16(a_q, bf, (f32x4){0.f,0.f,0.f,0.f}, 0, 0, 0);
      #pragma unroll
      for (int r = 0; r < 4; ++r) {
        float p = __expf(s4[r] * scale);
        l_acc[r] += p;
        bf16 hb = __float2bfloat16(p);
        Pl[w][quad * 4 + r][st * 16 + l16] = *reinterpret_cast<short*>(&hb);
      }
    }
    asm volatile("s_waitcnt lgkmcnt(0)" ::: "memory");
    #pragma unroll
    for (int kh = 0; kh < 2; ++kh) {
      short8 a_p = *(short8*)&Pl[w][l16][kh * 32 + quad * 8];
      #pragma unroll
      for (int nt = 0; nt < 2; ++nt) {
        short8 b_v = *(short8*)&Vt[nt * 16 + l16][kh * 32 + quad * 8];
        o_acc[nt] = __builtin_amdgcn_mfma_f32_16x16x32_bf16(a_p, b_v, o_acc[nt], 0, 0, 0);
      }
    }
    __syncthreads();
  }
  #pragma unroll
  for (int r = 0; r < 4; ++r) {
    float lv = l_acc[r];
    lv += __shfl_xor(lv, 1, 64);
    lv += __shfl_xor(lv, 2, 64);
    lv += __shfl_xor(lv, 4, 64);
    lv += __shfl_xor(lv, 8, 64);
    l_acc[r] = 1.0f / lv;
  }
  #pragma unroll
  for (int nt = 0; nt < 2; ++nt)
    #pragma unroll
    for (int r = 0; r < 4; ++r)
      o[((size_t)(b * M_) + qt * 64 + w * 16 + quad * 4 + r) * D_ + h * 32 + nt * 16 + l16] =
          __float2bfloat16(o_acc[nt][r] * l_acc[r]);
}

// ---------------- fused s head: 8 waves, both triangle tiles in parallel (unchanged) ----------------
__global__ __launch_bounds__(512) void k_shead_f(const bf16* __restrict__ q3,
    const bf16* __restrict__ k3, const float* __restrict__ snw, const float* __restrict__ snb,
    const float* __restrict__ sfw, const float* __restrict__ sfb, float* __restrict__ outs)
{
  int p = blockIdx.x, b = blockIdx.z;
  int it = 0;
  while ((it + 1) * (it + 2) / 2 <= p) ++it;
  int jt = p - it * (it + 1) / 2;
  int t = threadIdx.x;
  int half = t >> 8;          // 0 -> Sa, 1 -> Sb
  int tl = t & 255;
  int w = tl >> 6, lane = tl & 63;
  int quad = lane >> 4, l16 = lane & 15;
  __shared__ float Sa[64][65], Sb[64][65];
  const float scale = 0.17677669529663687f;
  float wsn[H_], bsn[H_], wsf[H_];
  #pragma unroll
  for (int h = 0; h < H_; ++h) { wsn[h] = snw[h]; bsn[h] = snb[h]; wsf[h] = sfw[h]; }
  float bias0 = sfb[0];
  int rt = half ? jt : it;    // q-row tile
  int ct = half ? it : jt;    // k-col tile  (diag: both halves compute identical values)
  float (*S)[65] = half ? Sb : Sa;
  short8 aqs[H_];
  #pragma unroll
  for (int h = 0; h < H_; ++h)
    aqs[h] = *(const short8*)&q3[((size_t)(b * M_) + rt * 64 + w * 16 + l16) * D_ + h * 32 + quad * 8];
  #pragma unroll
  for (int cf = 0; cf < 4; ++cf) {
    f32x4 s4[H_];
    #pragma unroll
    for (int h = 0; h < H_; ++h) {
      short8 bk = *(const short8*)&k3[((size_t)(b * M_) + ct * 64 + cf * 16 + l16) * D_ + h * 32 + quad * 8];
      s4[h] = __builtin_amdgcn_mfma_f32_16x16x32_bf16(aqs[h], bk, (f32x4){0.f,0.f,0.f,0.f}, 0, 0, 0);
    }
    #pragma unroll
    for (int r = 0; r < 4; ++r) {
      float d8[H_], ssum = 0.f, ssq = 0.f;
      #pragma unroll
      for (int h = 0; h < H_; ++h) {
        float s = s4[h][r] * scale;
        d8[h] = s; ssum += s; ssq += s * s;
      }
      float mu = ssum * 0.125f;
      float var = ssq * 0.125f - mu * mu;
      float rstd = rsqrtf(var + 1e-5f);
      float val = bias0;
      #pragma unroll
      for (int h = 0; h < H_; ++h)
        val += ((d8[h] - mu) * rstd * wsn[h] + bsn[h]) * wsf[h];
      S[w * 16 + quad * 4 + r][cf * 16 + l16] = val;
    }
  }
  __syncthreads();
  bool diag = (it == jt);
  int i = tl >> 2, j0 = (tl & 3) * 16;
  if (half == 0) {
    #pragma unroll
    for (int jj = 0; jj < 16; ++jj) {
      int j = j0 + jj;
      outs[((size_t)(b * M_) + it * 64 + i) * M_ + jt * 64 + j] = 0.5f * (Sa[i][j] + Sb[j][i]);
    }
  } else if (!diag) {
    #pragma unroll
    for (int ii = 0; ii < 16; ++ii) {
      int i2 = j0 + ii;
      outs[((size_t)(b * M_) + jt * 64 + i) * M_ + it * 64 + i2] = 0.5f * (Sb[i][i2] + Sa[i2][i]);
    }
  }
}

extern "C" void kernel_launch(void* const* d_in, const int* in_sizes, int n_in,
                              void* d_out, int out_size, void* d_ws, size_t ws_size,
                              hipStream_t stream)
{
  const float* X    = (const float*)d_in[0];
  const float* fW   = (const float*)d_in[2];
  const float* fb   = (const float*)d_in[3];
  const float* cW   = (const float*)d_in[4];
  const float* cb   = (const float*)d_in[5];
  const float* Wq   = (const float*)d_in[6];
  const float* bq   = (const float*)d_in[7];
  const float* Wk   = (const float*)d_in[8];
  const float* bk   = (const float*)d_in[9];
  const float* Wv   = (const float*)d_in[10];
  const float* bv   = (const float*)d_in[11];
  const float* Wo   = (const float*)d_in[12];
  const float* bo   = (const float*)d_in[13];
  const float* ln1w = (const float*)d_in[14];
  const float* ln1b = (const float*)d_in[15];
  const float* ln2w = (const float*)d_in[16];
  const float* ln2b = (const float*)d_in[17];
  const float* lnfw = (const float*)d_in[18];
  const float* lnfb = (const float*)d_in[19];
  const float* uw   = (const float*)d_in[20];
  const float* ub   = (const float*)d_in[21];
  const float* dw   = (const float*)d_in[22];
  const float* db   = (const float*)d_in[23];
  const float* finw = (const float*)d_in[24];
  const float* finb = (const float*)d_in[25];
  const float* snw  = (const float*)d_in[26];
  const float* snb  = (const float*)d_in[27];
  const float* sfw  = (const float*)d_in[28];
  const float* sfb  = (const float*)d_in[29];

  char* base = (char*)d_ws;
  const size_t MiB = 1024 * 1024;
  bf16* q_b   = (bf16*)(base + 0 * MiB);              // layer-3 q lives until s head
  bf16* k_b   = (bf16*)(base + 2 * MiB);              // layer-3 k lives until s head
  bf16* wqkvt = (bf16*)(base + 4 * MiB);              // 1.5 MiB
  bf16* wot   = (bf16*)(base + 5 * MiB + 512 * 1024); // 512 KiB
  bf16* uwt   = (bf16*)(base + 6 * MiB);              // 2 MiB
  bf16* dwt   = (bf16*)(base + 8 * MiB);              // 2 MiB
  bf16* fwt   = (bf16*)(base + 10 * MiB);             // 32 KiB
  float* x    = (float*)(base + 10 * MiB + 512 * 1024); // 4 MiB
  char* SR    = base + 14 * MiB + 512 * 1024;
  bf16* xn_b  = (bf16*)(SR + 0 * MiB);
  bf16* v_b   = (bf16*)(SR + 2 * MiB);
  bf16* att_b = (bf16*)(SR + 4 * MiB);
  bf16* h1_b  = (bf16*)(SR + 6 * MiB);                // 8 MiB
  float* outx = (float*)d_out;
  float* outs = outx + (size_t)BM_TOT * 64;

  dim3 blk(256);
  dim3 blk512(512);
  wconv_all<<<dim3(772), blk, 0, stream>>>(Wq, Wk, Wv, Wo, uw, dw, finw,
                                           wqkvt, wot, uwt, dwt, fwt);
  k_embed<<<dim3(BM_TOT / 4), blk, 0, stream>>>(X, fW, fb, cW, cb, x);
  for (int l = 0; l < L_; ++l) {
    k_ln<<<dim3(BM_TOT / 4), blk, 0, stream>>>(x, ln1w + l * D_, ln1b + l * D_, xn_b);
    mgemm_qkv<<<dim3(12, 64), blk, 0, stream>>>(xn_b, wqkvt + (size_t)l * 196608,
                                                bq + l * D_, bk + l * D_, bv + l * D_,
                                                q_b, k_b, v_b);
    k_flash<<<dim3(16, H_, B_), blk, 0, stream>>>(q_b, k_b, v_b, att_b);
    mgemm512<<<dim3(4, 64), blk512, 0, stream>>>(att_b, wot + (size_t)l * 65536, bo + l * D_,
                                                 x, x, nullptr, 256, 256, 2 | 8);
    k_ln<<<dim3(BM_TOT / 4), blk, 0, stream>>>(x, ln2w + l * D_, ln2b + l * D_, xn_b);
    mgemm<<<dim3(16, 64), blk, 0, stream>>>(xn_b, uwt + (size_t)l * 262144, ub + l * DFF_,
                                            nullptr, nullptr, h1_b, 256, 1024, 1 | 4);
    mgemm512<<<dim3(4, 64), blk512, 0, stream>>>(h1_b, dwt + (size_t)l * 262144, db + l * D_,
                                                 x, x, nullptr, 1024, 256, 2 | 8);
  }
  k_ln<<<dim3(BM_TOT / 4), blk, 0, stream>>>(x, lnfw, lnfb, xn_b);
  mgemm512<<<dim3(1, 64), blk512, 0, stream>>>(xn_b, fwt, finb, nullptr, outx, nullptr, 256, 64, 8);
  // layer-3 q/k still live in q_b/k_b
  k_shead_f<<<dim3(136, 1, B_), blk512, 0, stream>>>(q_b, k_b, snw, snb, sfw, sfb, outs);
}

// Round 9
// 404.031 us; speedup vs baseline: 1.1784x; 1.0372x over previous
//
#include <hip/hip_runtime.h>
#include <hip/hip_bf16.h>
#include <math.h>

#define B_ 4
#define M_ 1024
#define NIN 70
#define D_ 256
#define H_ 8
#define L_ 4
#define DFF_ 1024
#define BM_TOT 4096

typedef __hip_bfloat16 bf16;
typedef short short8 __attribute__((ext_vector_type(8)));
typedef float f32x4 __attribute__((ext_vector_type(4)));

// ---------------- single-launch weight convert+transpose ----------------
__global__ __launch_bounds__(256) void wconv_all(
    const float* __restrict__ Wq, const float* __restrict__ Wk, const float* __restrict__ Wv,
    const float* __restrict__ Wo, const float* __restrict__ uw, const float* __restrict__ dw,
    const float* __restrict__ finw,
    bf16* __restrict__ wqkvt, bf16* __restrict__ wot, bf16* __restrict__ uwt,
    bf16* __restrict__ dwt, bf16* __restrict__ fwt)
{
  __shared__ float T[64][65];
  int idx = blockIdx.x;
  const float* src; bf16* dst; int K, N, k0, n0, rbase, S;
  if (idx < 192) {            // Wq/Wk/Wv -> wqkvt[l][m*256 + n][k]
    int m = idx >> 6; int r = idx & 63; int l = r >> 4; int tt = r & 15;
    int kt = tt >> 2, nt = tt & 3;
    src = (m == 0 ? Wq : (m == 1 ? Wk : Wv)) + (size_t)l * 65536;
    K = 256; N = 256; k0 = kt * 64; n0 = nt * 64;
    dst = wqkvt + (size_t)l * 196608; rbase = m * 256 + nt * 64; S = 256;
  } else if (idx < 256) {     // Wo
    int r = idx - 192; int l = r >> 4; int tt = r & 15; int kt = tt >> 2, nt = tt & 3;
    src = Wo + (size_t)l * 65536; K = 256; N = 256; k0 = kt * 64; n0 = nt * 64;
    dst = wot + (size_t)l * 65536; rbase = nt * 64; S = 256;
  } else if (idx < 512) {     // uw (256 x 1024)
    int r = idx - 256; int l = r >> 6; int tt = r & 63; int kt = tt >> 4, nt = tt & 15;
    src = uw + (size_t)l * 262144; K = 256; N = 1024; k0 = kt * 64; n0 = nt * 64;
    dst = uwt + (size_t)l * 262144; rbase = nt * 64; S = 256;
  } else if (idx < 768) {     // dw (1024 x 256)
    int r = idx - 512; int l = r >> 6; int tt = r & 63; int kt = tt >> 2, nt = tt & 3;
    src = dw + (size_t)l * 262144; K = 1024; N = 256; k0 = kt * 64; n0 = nt * 64;
    dst = dwt + (size_t)l * 262144; rbase = nt * 64; S = 1024;
  } else {                    // finw (256 x 64)
    int kt = idx - 768;
    src = finw; K = 256; N = 64; k0 = kt * 64; n0 = 0;
    dst = fwt; rbase = 0; S = 256;
  }
  int t = threadIdx.x;
  int kl = t >> 2, ns = (t & 3) * 16;
  #pragma unroll
  for (int i = 0; i < 16; i += 4)
    *(float4*)&T[kl][ns + i] = *(const float4*)&src[(size_t)(k0 + kl) * N + n0 + ns + i];
  __syncthreads();
  int nl = t >> 2, ks = (t & 3) * 16;
  __align__(16) bf16 tmp[16];
  #pragma unroll
  for (int i = 0; i < 16; ++i) tmp[i] = __float2bfloat16(T[ks + i][nl]);
  *(uint4*)&dst[(size_t)(rbase + nl) * S + k0 + ks] = *(uint4*)&tmp[0];
  *(uint4*)&dst[(size_t)(rbase + nl) * S + k0 + ks + 8] = *(uint4*)&tmp[8];
}

// ---------------- embedding: 4 rows/block ----------------
__global__ __launch_bounds__(256) void k_embed(const float* __restrict__ X,
    const float* __restrict__ fW, const float* __restrict__ fb,
    const float* __restrict__ cW, const float* __restrict__ cb,
    float* __restrict__ x)
{
  int bm0 = blockIdx.x * 4;
  int d = threadIdx.x;
  __shared__ float xr[4][NIN];
  for (int i = d; i < 4 * NIN; i += 256)
    xr[i / NIN][i % NIN] = X[(size_t)(bm0 + i / NIN) * NIN + i % NIN];
  __syncthreads();
  int f = d & 127;
  float fw0 = fW[f * 3 + 0], fw1 = fW[f * 3 + 1], fw2 = fW[f * 3 + 2], fbv = fb[f];
  float cbv = cb[d];
  float acc[4];
  #pragma unroll
  for (int r = 0; r < 4; ++r) {
    float proj = xr[r][0] * fw0 + xr[r][1] * fw1 + xr[r][2] * fw2 + fbv;
    acc[r] = (d < 128 ? cosf(proj) : sinf(proj)) * 0.17677669529663687f + cbv;
  }
  #pragma unroll 8
  for (int c = 0; c < 64; ++c) {
    float cw = cW[c * D_ + d];
    #pragma unroll
    for (int r = 0; r < 4; ++r) acc[r] += xr[r][6 + c] * cw;
  }
  #pragma unroll
  for (int r = 0; r < 4; ++r)
    x[(size_t)(bm0 + r) * D_ + d] = acc[r];
}

// ---------------- layernorm: fp32 in -> bf16 out ----------------
__global__ __launch_bounds__(256) void k_ln(const float* __restrict__ xin,
    const float* __restrict__ w, const float* __restrict__ b, bf16* __restrict__ xout)
{
  int wave = threadIdx.x >> 6;
  int lane = threadIdx.x & 63;
  int row = blockIdx.x * 4 + wave;
  float4 xv = *(const float4*)&xin[row * D_ + lane * 4];
  float s = xv.x + xv.y + xv.z + xv.w;
  float q = xv.x * xv.x + xv.y * xv.y + xv.z * xv.z + xv.w * xv.w;
  #pragma unroll
  for (int off = 32; off; off >>= 1) {
    s += __shfl_xor(s, off, 64);
    q += __shfl_xor(q, off, 64);
  }
  float mu = s * (1.0f / D_);
  float var = q * (1.0f / D_) - mu * mu;
  float rstd = rsqrtf(var + 1e-5f);
  float4 wv = *(const float4*)&w[lane * 4];
  float4 bv = *(const float4*)&b[lane * 4];
  __align__(8) bf16 tmp[4];
  tmp[0] = __float2bfloat16((xv.x - mu) * rstd * wv.x + bv.x);
  tmp[1] = __float2bfloat16((xv.y - mu) * rstd * wv.y + bv.y);
  tmp[2] = __float2bfloat16((xv.z - mu) * rstd * wv.z + bv.z);
  tmp[3] = __float2bfloat16((xv.w - mu) * rstd * wv.w + bv.w);
  *(uint2*)&xout[row * D_ + lane * 4] = *(uint2*)tmp;
}

// ---------------- MFMA GEMM (reg-prefetch, BK=64; used for uw) ----------------
__global__ __launch_bounds__(256) void mgemm(const bf16* __restrict__ Ab,
    const bf16* __restrict__ Wt, const float* __restrict__ bias,
    const float* __restrict__ Res, float* __restrict__ Cf, bf16* __restrict__ Cb,
    int K, int N, int flags)
{
  __shared__ short As[64][72];
  __shared__ short Bs[64][72];
  int t = threadIdx.x;
  int m0 = blockIdx.y * 64, n0 = blockIdx.x * 64;
  int w = t >> 6, lane = t & 63;
  int srow = t >> 2, sseg = (t & 3) * 16;
  f32x4 acc[4] = {{0.f,0.f,0.f,0.f},{0.f,0.f,0.f,0.f},{0.f,0.f,0.f,0.f},{0.f,0.f,0.f,0.f}};
  int mf = w * 16 + (lane & 15);
  int kf = (lane >> 4) * 8;
  const bf16* pA = Ab + (size_t)(m0 + srow) * K + sseg;
  const bf16* pB = Wt + (size_t)(n0 + srow) * K + sseg;
  uint4 ra0 = *(const uint4*)pA, ra1 = *(const uint4*)(pA + 8);
  uint4 rb0 = *(const uint4*)pB, rb1 = *(const uint4*)(pB + 8);
  for (int k0 = 0; k0 < K; k0 += 64) {
    *(uint4*)&As[srow][sseg] = ra0;
    *(uint4*)&As[srow][sseg + 8] = ra1;
    *(uint4*)&Bs[srow][sseg] = rb0;
    *(uint4*)&Bs[srow][sseg + 8] = rb1;
    __syncthreads();
    if (k0 + 64 < K) {
      ra0 = *(const uint4*)(pA + k0 + 64);
      ra1 = *(const uint4*)(pA + k0 + 72);
      rb0 = *(const uint4*)(pB + k0 + 64);
      rb1 = *(const uint4*)(pB + k0 + 72);
    }
    #pragma unroll
    for (int kk = 0; kk < 64; kk += 32) {
      short8 a = *(short8*)&As[mf][kk + kf];
      #pragma unroll
      for (int nt = 0; nt < 4; ++nt) {
        short8 bfr = *(short8*)&Bs[nt * 16 + (lane & 15)][kk + kf];
        acc[nt] = __builtin_amdgcn_mfma_f32_16x16x32_bf16(a, bfr, acc[nt], 0, 0, 0);
      }
    }
    __syncthreads();
  }
  int row0 = m0 + w * 16 + (lane >> 4) * 4;
  #pragma unroll
  for (int nt = 0; nt < 4; ++nt) {
    int col = n0 + nt * 16 + (lane & 15);
    float bs = bias[col];
    #pragma unroll
    for (int r = 0; r < 4; ++r) {
      float v = acc[nt][r] + bs;
      if (flags & 1) v = 0.5f * v * (1.0f + erff(v * 0.70710678118654752f));
      if (flags & 2) v += Res[(size_t)(row0 + r) * N + col];
      if (flags & 8) Cf[(size_t)(row0 + r) * N + col] = v;
      if (flags & 4) Cb[(size_t)(row0 + r) * N + col] = __float2bfloat16(v);
    }
  }
}

// ---------------- MFMA GEMM, 512 thr / 8 waves, BK=64, LDS double-buffer ----------------
// One barrier per K-step: write buf[cur^1] (tile i+1) while MFMA reads buf[cur];
// end-of-iter barrier protects next reads of cur^1 AND iter i+2's overwrite of cur.
// Depth-2 register prefetch. Grid = 256 blocks (1/CU) so 73.7 KB LDS costs nothing.
__global__ __launch_bounds__(512) void mgemm512(const bf16* __restrict__ Ab,
    const bf16* __restrict__ Wt, const float* __restrict__ bias,
    const float* __restrict__ Res, float* __restrict__ Cf, bf16* __restrict__ Cb,
    int K, int N, int flags)
{
  __shared__ short As[2][64][72];
  __shared__ short Bs[2][64][72];
  int t = threadIdx.x;
  int m0 = blockIdx.y * 64, n0 = blockIdx.x * 64;
  int w = t >> 6, lane = t & 63;
  int l16 = lane & 15, quad = lane >> 4;
  int s = t & 255;
  int srow = s >> 2, sseg = (s & 3) * 16;
  bool isA = (t < 256);
  const bf16* pS = (isA ? Ab + (size_t)(m0 + srow) * K
                        : Wt + (size_t)(n0 + srow) * K) + sseg;
  uint4 ra0 = *(const uint4*)pS, ra1 = *(const uint4*)(pS + 8);
  {
    short (*S)[72] = isA ? As[0] : Bs[0];
    *(uint4*)&S[srow][sseg] = ra0;
    *(uint4*)&S[srow][sseg + 8] = ra1;
  }
  int nsteps = K >> 6;
  if (nsteps > 1) {
    ra0 = *(const uint4*)(pS + 64);
    ra1 = *(const uint4*)(pS + 72);
  }
  __syncthreads();
  f32x4 acc[2] = {{0.f,0.f,0.f,0.f},{0.f,0.f,0.f,0.f}};
  int mf = (w & 3) * 16 + l16;
  int kf = quad * 8;
  int ntb = (w >> 2) * 2;
  for (int i = 0; i < nsteps; ++i) {
    int cur = i & 1;
    if (i + 1 < nsteps) {
      short (*S)[72] = isA ? As[cur ^ 1] : Bs[cur ^ 1];
      *(uint4*)&S[srow][sseg] = ra0;
      *(uint4*)&S[srow][sseg + 8] = ra1;
      if (i + 2 < nsteps) {
        ra0 = *(const uint4*)(pS + (size_t)(i + 2) * 64);
        ra1 = *(const uint4*)(pS + (size_t)(i + 2) * 64 + 8);
      }
    }
    #pragma unroll
    for (int kk = 0; kk < 64; kk += 32) {
      short8 a = *(short8*)&As[cur][mf][kk + kf];
      #pragma unroll
      for (int j = 0; j < 2; ++j) {
        short8 bfr = *(short8*)&Bs[cur][(ntb + j) * 16 + l16][kk + kf];
        acc[j] = __builtin_amdgcn_mfma_f32_16x16x32_bf16(a, bfr, acc[j], 0, 0, 0);
      }
    }
    __syncthreads();
  }
  int row0 = m0 + (w & 3) * 16 + quad * 4;
  #pragma unroll
  for (int j = 0; j < 2; ++j) {
    int col = n0 + (ntb + j) * 16 + l16;
    float bs = bias[col];
    #pragma unroll
    for (int r = 0; r < 4; ++r) {
      float v = acc[j][r] + bs;
      if (flags & 1) v = 0.5f * v * (1.0f + erff(v * 0.70710678118654752f));
      if (flags & 2) v += Res[(size_t)(row0 + r) * N + col];
      if (flags & 8) Cf[(size_t)(row0 + r) * N + col] = v;
      if (flags & 4) Cb[(size_t)(row0 + r) * N + col] = __float2bfloat16(v);
    }
  }
}

// ---------------- fused QKV MFMA GEMM (reg-prefetch, BK=64; unchanged) ----------------
__global__ __launch_bounds__(256) void mgemm_qkv(const bf16* __restrict__ Ab,
    const bf16* __restrict__ Wt, const float* __restrict__ bq,
    const float* __restrict__ bk, const float* __restrict__ bv,
    bf16* __restrict__ qo, bf16* __restrict__ ko, bf16* __restrict__ vo)
{
  __shared__ short As[64][72];
  __shared__ short Bs[64][72];
  int t = threadIdx.x;
  int m0 = blockIdx.y * 64, n0g = blockIdx.x * 64;
  int w = t >> 6, lane = t & 63;
  int srow = t >> 2, sseg = (t & 3) * 16;
  f32x4 acc[4] = {{0.f,0.f,0.f,0.f},{0.f,0.f,0.f,0.f},{0.f,0.f,0.f,0.f},{0.f,0.f,0.f,0.f}};
  int mf = w * 16 + (lane & 15);
  int kf = (lane >> 4) * 8;
  const bf16* pA = Ab + (size_t)(m0 + srow) * 256 + sseg;
  const bf16* pB = Wt + (size_t)(n0g + srow) * 256 + sseg;
  uint4 ra0 = *(const uint4*)pA, ra1 = *(const uint4*)(pA + 8);
  uint4 rb0 = *(const uint4*)pB, rb1 = *(const uint4*)(pB + 8);
  for (int k0 = 0; k0 < 256; k0 += 64) {
    *(uint4*)&As[srow][sseg] = ra0;
    *(uint4*)&As[srow][sseg + 8] = ra1;
    *(uint4*)&Bs[srow][sseg] = rb0;
    *(uint4*)&Bs[srow][sseg + 8] = rb1;
    __syncthreads();
    if (k0 + 64 < 256) {
      ra0 = *(const uint4*)(pA + k0 + 64);
      ra1 = *(const uint4*)(pA + k0 + 72);
      rb0 = *(const uint4*)(pB + k0 + 64);
      rb1 = *(const uint4*)(pB + k0 + 72);
    }
    #pragma unroll
    for (int kk = 0; kk < 64; kk += 32) {
      short8 a = *(short8*)&As[mf][kk + kf];
      #pragma unroll
      for (int nt = 0; nt < 4; ++nt) {
        short8 bfr = *(short8*)&Bs[nt * 16 + (lane & 15)][kk + kf];
        acc[nt] = __builtin_amdgcn_mfma_f32_16x16x32_bf16(a, bfr, acc[nt], 0, 0, 0);
      }
    }
    __syncthreads();
  }
  int seg = n0g >> 8;
  const float* bb = (seg == 0 ? bq : (seg == 1 ? bk : bv));
  bf16* dst = (seg == 0 ? qo : (seg == 1 ? ko : vo));
  int row0 = m0 + w * 16 + (lane >> 4) * 4;
  #pragma unroll
  for (int nt = 0; nt < 4; ++nt) {
    int col = (n0g & 255) + nt * 16 + (lane & 15);
    float bs = bb[col];
    #pragma unroll
    for (int r = 0; r < 4; ++r)
      dst[(size_t)(row0 + r) * 256 + col] = __float2bfloat16(acc[nt][r] + bs);
  }
}

// ---------------- MFMA flash attention: K/V LDS double-buffer, depth-2 prefetch ----------------
__global__ __launch_bounds__(256) void k_flash(const bf16* __restrict__ q,
    const bf16* __restrict__ k, const bf16* __restrict__ v, bf16* __restrict__ o)
{
  int qt = blockIdx.x, h = blockIdx.y, b = blockIdx.z;
  int t = threadIdx.x;
  int w = t >> 6, lane = t & 63;
  int quad = lane >> 4, l16 = lane & 15;
  __shared__ short Ks[2][64][40];
  __shared__ short Vt[2][32][76];
  __shared__ short Pl[4][16][72];
  short8 a_q = *(const short8*)&q[((size_t)(b * M_) + qt * 64 + w * 16 + l16) * D_ + h * 32 + quad * 8];
  f32x4 o_acc[2] = {{0.f,0.f,0.f,0.f},{0.f,0.f,0.f,0.f}};
  float l_acc[4] = {0.f, 0.f, 0.f, 0.f};
  int skey = t >> 2, sseg = t & 3;
  const float scale = 0.17677669529663687f;
  const bf16* pk = &k[((size_t)(b * M_) + skey) * D_ + h * 32 + sseg * 8];
  const bf16* pv = &v[((size_t)(b * M_) + skey) * D_ + h * 32 + sseg * 8];
  short8 rk = *(const short8*)pk;
  short8 rv = *(const short8*)pv;
  // stage tile 0 into buf0, prefetch tile 1
  *(short8*)&Ks[0][skey][sseg * 8] = rk;
  #pragma unroll
  for (int i = 0; i < 8; ++i) Vt[0][sseg * 8 + i][skey] = rv[i];
  rk = *(const short8*)(pk + (size_t)64 * D_);
  rv = *(const short8*)(pv + (size_t)64 * D_);
  __syncthreads();
  for (int kt = 0; kt < 16; ++kt) {
    int cur = kt & 1;
    if (kt < 15) {
      *(short8*)&Ks[cur ^ 1][skey][sseg * 8] = rk;
      #pragma unroll
      for (int i = 0; i < 8; ++i) Vt[cur ^ 1][sseg * 8 + i][skey] = rv[i];
      if (kt < 14) {
        rk = *(const short8*)(pk + (size_t)(kt + 2) * 64 * D_);
        rv = *(const short8*)(pv + (size_t)(kt + 2) * 64 * D_);
      }
    }
    #pragma unroll
    for (int st = 0; st < 4; ++st) {
      short8 bf = *(short8*)&Ks[cur][st * 16 + l16][quad * 8];
      f32x4 s4 = __builtin_amdgcn_mfma_f32_16x16x32_bf16(a_q, bf, (f32x4){0.f,0.f,0.f,0.f}, 0, 0, 0);
      #pragma unroll
      for (int r = 0; r < 4; ++r) {
        float p = __expf(s4[r] * scale);
        l_acc[r] += p;
        bf16 hb = __float2bfloat16(p);
        Pl[w][quad * 4 + r][st * 16 + l16] = *reinterpret_cast<short*>(&hb);
      }
    }
    asm volatile("s_waitcnt lgkmcnt(0)" ::: "memory");
    #pragma unroll
    for (int kh = 0; kh < 2; ++kh) {
      short8 a_p = *(short8*)&Pl[w][l16][kh * 32 + quad * 8];
      #pragma unroll
      for (int nt = 0; nt < 2; ++nt) {
        short8 b_v = *(short8*)&Vt[cur][nt * 16 + l16][kh * 32 + quad * 8];
        o_acc[nt] = __builtin_amdgcn_mfma_f32_16x16x32_bf16(a_p, b_v, o_acc[nt], 0, 0, 0);
      }
    }
    __syncthreads();
  }
  #pragma unroll
  for (int r = 0; r < 4; ++r) {
    float lv = l_acc[r];
    lv += __shfl_xor(lv, 1, 64);
    lv += __shfl_xor(lv, 2, 64);
    lv += __shfl_xor(lv, 4, 64);
    lv += __shfl_xor(lv, 8, 64);
    l_acc[r] = 1.0f / lv;
  }
  #pragma unroll
  for (int nt = 0; nt < 2; ++nt)
    #pragma unroll
    for (int r = 0; r < 4; ++r)
      o[((size_t)(b * M_) + qt * 64 + w * 16 + quad * 4 + r) * D_ + h * 32 + nt * 16 + l16] =
          __float2bfloat16(o_acc[nt][r] * l_acc[r]);
}

// ---------------- fused s head: 8 waves, both triangle tiles in parallel (unchanged) ----------------
__global__ __launch_bounds__(512) void k_shead_f(const bf16* __restrict__ q3,
    const bf16* __restrict__ k3, const float* __restrict__ snw, const float* __restrict__ snb,
    const float* __restrict__ sfw, const float* __restrict__ sfb, float* __restrict__ outs)
{
  int p = blockIdx.x, b = blockIdx.z;
  int it = 0;
  while ((it + 1) * (it + 2) / 2 <= p) ++it;
  int jt = p - it * (it + 1) / 2;
  int t = threadIdx.x;
  int half = t >> 8;          // 0 -> Sa, 1 -> Sb
  int tl = t & 255;
  int w = tl >> 6, lane = tl & 63;
  int quad = lane >> 4, l16 = lane & 15;
  __shared__ float Sa[64][65], Sb[64][65];
  const float scale = 0.17677669529663687f;
  float wsn[H_], bsn[H_], wsf[H_];
  #pragma unroll
  for (int h = 0; h < H_; ++h) { wsn[h] = snw[h]; bsn[h] = snb[h]; wsf[h] = sfw[h]; }
  float bias0 = sfb[0];
  int rt = half ? jt : it;    // q-row tile
  int ct = half ? it : jt;    // k-col tile  (diag: both halves compute identical values)
  float (*S)[65] = half ? Sb : Sa;
  short8 aqs[H_];
  #pragma unroll
  for (int h = 0; h < H_; ++h)
    aqs[h] = *(const short8*)&q3[((size_t)(b * M_) + rt * 64 + w * 16 + l16) * D_ + h * 32 + quad * 8];
  #pragma unroll
  for (int cf = 0; cf < 4; ++cf) {
    f32x4 s4[H_];
    #pragma unroll
    for (int h = 0; h < H_; ++h) {
      short8 bk = *(const short8*)&k3[((size_t)(b * M_) + ct * 64 + cf * 16 + l16) * D_ + h * 32 + quad * 8];
      s4[h] = __builtin_amdgcn_mfma_f32_16x16x32_bf16(aqs[h], bk, (f32x4){0.f,0.f,0.f,0.f}, 0, 0, 0);
    }
    #pragma unroll
    for (int r = 0; r < 4; ++r) {
      float d8[H_], ssum = 0.f, ssq = 0.f;
      #pragma unroll
      for (int h = 0; h < H_; ++h) {
        float s = s4[h][r] * scale;
        d8[h] = s; ssum += s; ssq += s * s;
      }
      float mu = ssum * 0.125f;
      float var = ssq * 0.125f - mu * mu;
      float rstd = rsqrtf(var + 1e-5f);
      float val = bias0;
      #pragma unroll
      for (int h = 0; h < H_; ++h)
        val += ((d8[h] - mu) * rstd * wsn[h] + bsn[h]) * wsf[h];
      S[w * 16 + quad * 4 + r][cf * 16 + l16] = val;
    }
  }
  __syncthreads();
  bool diag = (it == jt);
  int i = tl >> 2, j0 = (tl & 3) * 16;
  if (half == 0) {
    #pragma unroll
    for (int jj = 0; jj < 16; ++jj) {
      int j = j0 + jj;
      outs[((size_t)(b * M_) + it * 64 + i) * M_ + jt * 64 + j] = 0.5f * (Sa[i][j] + Sb[j][i]);
    }
  } else if (!diag) {
    #pragma unroll
    for (int ii = 0; ii < 16; ++ii) {
      int i2 = j0 + ii;
      outs[((size_t)(b * M_) + jt * 64 + i) * M_ + it * 64 + i2] = 0.5f * (Sb[i][i2] + Sa[i2][i]);
    }
  }
}

extern "C" void kernel_launch(void* const* d_in, const int* in_sizes, int n_in,
                              void* d_out, int out_size, void* d_ws, size_t ws_size,
                              hipStream_t stream)
{
  const float* X    = (const float*)d_in[0];
  const float* fW   = (const float*)d_in[2];
  const float* fb   = (const float*)d_in[3];
  const float* cW   = (const float*)d_in[4];
  const float* cb   = (const float*)d_in[5];
  const float* Wq   = (const float*)d_in[6];
  const float* bq   = (const float*)d_in[7];
  const float* Wk   = (const float*)d_in[8];
  const float* bk   = (const float*)d_in[9];
  const float* Wv   = (const float*)d_in[10];
  const float* bv   = (const float*)d_in[11];
  const float* Wo   = (const float*)d_in[12];
  const float* bo   = (const float*)d_in[13];
  const float* ln1w = (const float*)d_in[14];
  const float* ln1b = (const float*)d_in[15];
  const float* ln2w = (const float*)d_in[16];
  const float* ln2b = (const float*)d_in[17];
  const float* lnfw = (const float*)d_in[18];
  const float* lnfb = (const float*)d_in[19];
  const float* uw   = (const float*)d_in[20];
  const float* ub   = (const float*)d_in[21];
  const float* dw   = (const float*)d_in[22];
  const float* db   = (const float*)d_in[23];
  const float* finw = (const float*)d_in[24];
  const float* finb = (const float*)d_in[25];
  const float* snw  = (const float*)d_in[26];
  const float* snb  = (const float*)d_in[27];
  const float* sfw  = (const float*)d_in[28];
  const float* sfb  = (const float*)d_in[29];

  char* base = (char*)d_ws;
  const size_t MiB = 1024 * 1024;
  bf16* q_b   = (bf16*)(base + 0 * MiB);              // layer-3 q lives until s head
  bf16* k_b   = (bf16*)(base + 2 * MiB);              // layer-3 k lives until s head
  bf16* wqkvt = (bf16*)(base + 4 * MiB);              // 1.5 MiB
  bf16* wot   = (bf16*)(base + 5 * MiB + 512 * 1024); // 512 KiB
  bf16* uwt   = (bf16*)(base + 6 * MiB);              // 2 MiB
  bf16* dwt   = (bf16*)(base + 8 * MiB);              // 2 MiB
  bf16* fwt   = (bf16*)(base + 10 * MiB);             // 32 KiB
  float* x    = (float*)(base + 10 * MiB + 512 * 1024); // 4 MiB
  char* SR    = base + 14 * MiB + 512 * 1024;
  bf16* xn_b  = (bf16*)(SR + 0 * MiB);
  bf16* v_b   = (bf16*)(SR + 2 * MiB);
  bf16* att_b = (bf16*)(SR + 4 * MiB);
  bf16* h1_b  = (bf16*)(SR + 6 * MiB);                // 8 MiB
  float* outx = (float*)d_out;
  float* outs = outx + (size_t)BM_TOT * 64;

  dim3 blk(256);
  dim3 blk512(512);
  wconv_all<<<dim3(772), blk, 0, stream>>>(Wq, Wk, Wv, Wo, uw, dw, finw,
                                           wqkvt, wot, uwt, dwt, fwt);
  k_embed<<<dim3(BM_TOT / 4), blk, 0, stream>>>(X, fW, fb, cW, cb, x);
  for (int l = 0; l < L_; ++l) {
    k_ln<<<dim3(BM_TOT / 4), blk, 0, stream>>>(x, ln1w + l * D_, ln1b + l * D_, xn_b);
    mgemm_qkv<<<dim3(12, 64), blk, 0, stream>>>(xn_b, wqkvt + (size_t)l * 196608,
                                                bq + l * D_, bk + l * D_, bv + l * D_,
                                                q_b, k_b, v_b);
    k_flash<<<dim3(16, H_, B_), blk, 0, stream>>>(q_b, k_b, v_b, att_b);
    mgemm512<<<dim3(4, 64), blk512, 0, stream>>>(att_b, wot + (size_t)l * 65536, bo + l * D_,
                                                 x, x, nullptr, 256, 256, 2 | 8);
    k_ln<<<dim3(BM_TOT / 4), blk, 0, stream>>>(x, ln2w + l * D_, ln2b + l * D_, xn_b);
    mgemm<<<dim3(16, 64), blk, 0, stream>>>(xn_b, uwt + (size_t)l * 262144, ub + l * DFF_,
                                            nullptr, nullptr, h1_b, 256, 1024, 1 | 4);
    mgemm512<<<dim3(4, 64), blk512, 0, stream>>>(h1_b, dwt + (size_t)l * 262144, db + l * D_,
                                                 x, x, nullptr, 1024, 256, 2 | 8);
  }
  k_ln<<<dim3(BM_TOT / 4), blk, 0, stream>>>(x, lnfw, lnfb, xn_b);
  mgemm512<<<dim3(1, 64), blk512, 0, stream>>>(xn_b, fwt, finb, nullptr, outx, nullptr, 256, 64, 8);
  // layer-3 q/k still live in q_b/k_b
  k_shead_f<<<dim3(136, 1, B_), blk512, 0, stream>>>(q_b, k_b, snw, snb, sfw, sfb, outs);
}

// Round 10
// 400.036 us; speedup vs baseline: 1.1902x; 1.0100x over previous
//
#include <hip/hip_runtime.h>
#include <hip/hip_bf16.h>
#include <math.h>

#define B_ 4
#define M_ 1024
#define NIN 70
#define D_ 256
#define H_ 8
#define L_ 4
#define DFF_ 1024
#define BM_TOT 4096

typedef __hip_bfloat16 bf16;
typedef short short8 __attribute__((ext_vector_type(8)));
typedef float f32x4 __attribute__((ext_vector_type(4)));

// ---------------- merged: weight convert+transpose (idx<772) | embedding (idx>=772) ----------------
__global__ __launch_bounds__(256) void wconv_embed(
    const float* __restrict__ Wq, const float* __restrict__ Wk, const float* __restrict__ Wv,
    const float* __restrict__ Wo, const float* __restrict__ uw, const float* __restrict__ dw,
    const float* __restrict__ finw,
    bf16* __restrict__ wqkvt, bf16* __restrict__ wot, bf16* __restrict__ uwt,
    bf16* __restrict__ dwt, bf16* __restrict__ fwt,
    const float* __restrict__ X, const float* __restrict__ fW, const float* __restrict__ fb,
    const float* __restrict__ cW, const float* __restrict__ cb, float* __restrict__ x)
{
  __shared__ float T[64][65];
  __shared__ float xr[4][NIN];
  int idx = blockIdx.x;
  int t = threadIdx.x;
  if (idx >= 772) {
    // ---- embedding: 4 rows/block ----
    int bm0 = (idx - 772) * 4;
    int d = t;
    for (int i = d; i < 4 * NIN; i += 256)
      xr[i / NIN][i % NIN] = X[(size_t)(bm0 + i / NIN) * NIN + i % NIN];
    __syncthreads();
    int f = d & 127;
    float fw0 = fW[f * 3 + 0], fw1 = fW[f * 3 + 1], fw2 = fW[f * 3 + 2], fbv = fb[f];
    float cbv = cb[d];
    float acc[4];
    #pragma unroll
    for (int r = 0; r < 4; ++r) {
      float proj = xr[r][0] * fw0 + xr[r][1] * fw1 + xr[r][2] * fw2 + fbv;
      acc[r] = (d < 128 ? cosf(proj) : sinf(proj)) * 0.17677669529663687f + cbv;
    }
    #pragma unroll 8
    for (int c = 0; c < 64; ++c) {
      float cw = cW[c * D_ + d];
      #pragma unroll
      for (int r = 0; r < 4; ++r) acc[r] += xr[r][6 + c] * cw;
    }
    #pragma unroll
    for (int r = 0; r < 4; ++r)
      x[(size_t)(bm0 + r) * D_ + d] = acc[r];
    return;
  }
  // ---- weight convert ----
  const float* src; bf16* dst; int K, N, k0, n0, rbase, S;
  if (idx < 192) {            // Wq/Wk/Wv -> wqkvt[l][m*256 + n][k]
    int m = idx >> 6; int r = idx & 63; int l = r >> 4; int tt = r & 15;
    int kt = tt >> 2, nt = tt & 3;
    src = (m == 0 ? Wq : (m == 1 ? Wk : Wv)) + (size_t)l * 65536;
    K = 256; N = 256; k0 = kt * 64; n0 = nt * 64;
    dst = wqkvt + (size_t)l * 196608; rbase = m * 256 + nt * 64; S = 256;
  } else if (idx < 256) {     // Wo
    int r = idx - 192; int l = r >> 4; int tt = r & 15; int kt = tt >> 2, nt = tt & 3;
    src = Wo + (size_t)l * 65536; K = 256; N = 256; k0 = kt * 64; n0 = nt * 64;
    dst = wot + (size_t)l * 65536; rbase = nt * 64; S = 256;
  } else if (idx < 512) {     // uw (256 x 1024)
    int r = idx - 256; int l = r >> 6; int tt = r & 63; int kt = tt >> 4, nt = tt & 15;
    src = uw + (size_t)l * 262144; K = 256; N = 1024; k0 = kt * 64; n0 = nt * 64;
    dst = uwt + (size_t)l * 262144; rbase = nt * 64; S = 256;
  } else if (idx < 768) {     // dw (1024 x 256)
    int r = idx - 512; int l = r >> 6; int tt = r & 63; int kt = tt >> 2, nt = tt & 3;
    src = dw + (size_t)l * 262144; K = 1024; N = 256; k0 = kt * 64; n0 = nt * 64;
    dst = dwt + (size_t)l * 262144; rbase = nt * 64; S = 1024;
  } else {                    // finw (256 x 64)
    int kt = idx - 768;
    src = finw; K = 256; N = 64; k0 = kt * 64; n0 = 0;
    dst = fwt; rbase = 0; S = 256;
  }
  int kl = t >> 2, ns = (t & 3) * 16;
  #pragma unroll
  for (int i = 0; i < 16; i += 4)
    *(float4*)&T[kl][ns + i] = *(const float4*)&src[(size_t)(k0 + kl) * N + n0 + ns + i];
  __syncthreads();
  int nl = t >> 2, ks = (t & 3) * 16;
  __align__(16) bf16 tmp[16];
  #pragma unroll
  for (int i = 0; i < 16; ++i) tmp[i] = __float2bfloat16(T[ks + i][nl]);
  *(uint4*)&dst[(size_t)(rbase + nl) * S + k0 + ks] = *(uint4*)&tmp[0];
  *(uint4*)&dst[(size_t)(rbase + nl) * S + k0 + ks + 8] = *(uint4*)&tmp[8];
}

// ---------------- layernorm: fp32 in -> bf16 out ----------------
__global__ __launch_bounds__(256) void k_ln(const float* __restrict__ xin,
    const float* __restrict__ w, const float* __restrict__ b, bf16* __restrict__ xout)
{
  int wave = threadIdx.x >> 6;
  int lane = threadIdx.x & 63;
  int row = blockIdx.x * 4 + wave;
  float4 xv = *(const float4*)&xin[row * D_ + lane * 4];
  float s = xv.x + xv.y + xv.z + xv.w;
  float q = xv.x * xv.x + xv.y * xv.y + xv.z * xv.z + xv.w * xv.w;
  #pragma unroll
  for (int off = 32; off; off >>= 1) {
    s += __shfl_xor(s, off, 64);
    q += __shfl_xor(q, off, 64);
  }
  float mu = s * (1.0f / D_);
  float var = q * (1.0f / D_) - mu * mu;
  float rstd = rsqrtf(var + 1e-5f);
  float4 wv = *(const float4*)&w[lane * 4];
  float4 bv = *(const float4*)&b[lane * 4];
  __align__(8) bf16 tmp[4];
  tmp[0] = __float2bfloat16((xv.x - mu) * rstd * wv.x + bv.x);
  tmp[1] = __float2bfloat16((xv.y - mu) * rstd * wv.y + bv.y);
  tmp[2] = __float2bfloat16((xv.z - mu) * rstd * wv.z + bv.z);
  tmp[3] = __float2bfloat16((xv.w - mu) * rstd * wv.w + bv.w);
  *(uint2*)&xout[row * D_ + lane * 4] = *(uint2*)tmp;
}

// ---------------- MFMA GEMM, 512 thr / 8 waves, BK=64, LDS double-buffer (64x64 tile) ----------------
__global__ __launch_bounds__(512) void mgemm512(const bf16* __restrict__ Ab,
    const bf16* __restrict__ Wt, const float* __restrict__ bias,
    const float* __restrict__ Res, float* __restrict__ Cf, bf16* __restrict__ Cb,
    int K, int N, int flags)
{
  __shared__ short As[2][64][72];
  __shared__ short Bs[2][64][72];
  int t = threadIdx.x;
  int m0 = blockIdx.y * 64, n0 = blockIdx.x * 64;
  int w = t >> 6, lane = t & 63;
  int l16 = lane & 15, quad = lane >> 4;
  int s = t & 255;
  int srow = s >> 2, sseg = (s & 3) * 16;
  bool isA = (t < 256);
  const bf16* pS = (isA ? Ab + (size_t)(m0 + srow) * K
                        : Wt + (size_t)(n0 + srow) * K) + sseg;
  uint4 ra0 = *(const uint4*)pS, ra1 = *(const uint4*)(pS + 8);
  {
    short (*S)[72] = isA ? As[0] : Bs[0];
    *(uint4*)&S[srow][sseg] = ra0;
    *(uint4*)&S[srow][sseg + 8] = ra1;
  }
  int nsteps = K >> 6;
  if (nsteps > 1) {
    ra0 = *(const uint4*)(pS + 64);
    ra1 = *(const uint4*)(pS + 72);
  }
  __syncthreads();
  f32x4 acc[2] = {{0.f,0.f,0.f,0.f},{0.f,0.f,0.f,0.f}};
  int mf = (w & 3) * 16 + l16;
  int kf = quad * 8;
  int ntb = (w >> 2) * 2;
  for (int i = 0; i < nsteps; ++i) {
    int cur = i & 1;
    if (i + 1 < nsteps) {
      short (*S)[72] = isA ? As[cur ^ 1] : Bs[cur ^ 1];
      *(uint4*)&S[srow][sseg] = ra0;
      *(uint4*)&S[srow][sseg + 8] = ra1;
      if (i + 2 < nsteps) {
        ra0 = *(const uint4*)(pS + (size_t)(i + 2) * 64);
        ra1 = *(const uint4*)(pS + (size_t)(i + 2) * 64 + 8);
      }
    }
    #pragma unroll
    for (int kk = 0; kk < 64; kk += 32) {
      short8 a = *(short8*)&As[cur][mf][kk + kf];
      #pragma unroll
      for (int j = 0; j < 2; ++j) {
        short8 bfr = *(short8*)&Bs[cur][(ntb + j) * 16 + l16][kk + kf];
        acc[j] = __builtin_amdgcn_mfma_f32_16x16x32_bf16(a, bfr, acc[j], 0, 0, 0);
      }
    }
    __syncthreads();
  }
  int row0 = m0 + (w & 3) * 16 + quad * 4;
  #pragma unroll
  for (int j = 0; j < 2; ++j) {
    int col = n0 + (ntb + j) * 16 + l16;
    float bs = bias[col];
    #pragma unroll
    for (int r = 0; r < 4; ++r) {
      float v = acc[j][r] + bs;
      if (flags & 1) v = 0.5f * v * (1.0f + erff(v * 0.70710678118654752f));
      if (flags & 2) v += Res[(size_t)(row0 + r) * N + col];
      if (flags & 8) Cf[(size_t)(row0 + r) * N + col] = v;
      if (flags & 4) Cb[(size_t)(row0 + r) * N + col] = __float2bfloat16(v);
    }
  }
}

// ---------------- QKV GEMM: 64x128 tile, 512 thr, BK=64, dbuf, depth-2 prefetch ----------------
// Wave w: rows (w&3)*16, col-half (w>>2)*64 -> 4 fragments. Each 128-col block is
// entirely inside one q/k/v segment (128 | 256).
__global__ __launch_bounds__(512) void mgemm_qkv2(const bf16* __restrict__ Ab,
    const bf16* __restrict__ Wt, const float* __restrict__ bq,
    const float* __restrict__ bk, const float* __restrict__ bv,
    bf16* __restrict__ qo, bf16* __restrict__ ko, bf16* __restrict__ vo)
{
  __shared__ short As[2][64][72];
  __shared__ short Bs[2][128][72];
  int t = threadIdx.x;
  int m0 = blockIdx.y * 64, n0 = blockIdx.x * 128;
  int w = t >> 6, lane = t & 63;
  int l16 = lane & 15, quad = lane >> 4;
  int s = t & 255;
  int srow = s >> 2, sseg = (s & 3) * 16;
  bool isA = (t < 256);
  const int K = 256;
  const bf16* pA  = Ab + (size_t)(m0 + srow) * K + sseg;
  const bf16* pB0 = Wt + (size_t)(n0 + srow) * K + sseg;
  const bf16* pB1 = Wt + (size_t)(n0 + 64 + srow) * K + sseg;
  uint4 r0, r1, r2, r3;
  if (isA) {
    r0 = *(const uint4*)pA; r1 = *(const uint4*)(pA + 8);
    *(uint4*)&As[0][srow][sseg] = r0; *(uint4*)&As[0][srow][sseg + 8] = r1;
    r0 = *(const uint4*)(pA + 64); r1 = *(const uint4*)(pA + 72);
  } else {
    r0 = *(const uint4*)pB0; r1 = *(const uint4*)(pB0 + 8);
    r2 = *(const uint4*)pB1; r3 = *(const uint4*)(pB1 + 8);
    *(uint4*)&Bs[0][srow][sseg] = r0; *(uint4*)&Bs[0][srow][sseg + 8] = r1;
    *(uint4*)&Bs[0][srow + 64][sseg] = r2; *(uint4*)&Bs[0][srow + 64][sseg + 8] = r3;
    r0 = *(const uint4*)(pB0 + 64); r1 = *(const uint4*)(pB0 + 72);
    r2 = *(const uint4*)(pB1 + 64); r3 = *(const uint4*)(pB1 + 72);
  }
  __syncthreads();
  f32x4 acc[4] = {{0.f,0.f,0.f,0.f},{0.f,0.f,0.f,0.f},{0.f,0.f,0.f,0.f},{0.f,0.f,0.f,0.f}};
  int mf = (w & 3) * 16 + l16;
  int kf = quad * 8;
  int ncb = (w >> 2) * 64;
  const int nsteps = 4;
  for (int i = 0; i < nsteps; ++i) {
    int cur = i & 1;
    if (i + 1 < nsteps) {
      if (isA) {
        *(uint4*)&As[cur ^ 1][srow][sseg] = r0; *(uint4*)&As[cur ^ 1][srow][sseg + 8] = r1;
      } else {
        *(uint4*)&Bs[cur ^ 1][srow][sseg] = r0; *(uint4*)&Bs[cur ^ 1][srow][sseg + 8] = r1;
        *(uint4*)&Bs[cur ^ 1][srow + 64][sseg] = r2; *(uint4*)&Bs[cur ^ 1][srow + 64][sseg + 8] = r3;
      }
      if (i + 2 < nsteps) {
        size_t off = (size_t)(i + 2) * 64;
        if (isA) {
          r0 = *(const uint4*)(pA + off); r1 = *(const uint4*)(pA + off + 8);
        } else {
          r0 = *(const uint4*)(pB0 + off); r1 = *(const uint4*)(pB0 + off + 8);
          r2 = *(const uint4*)(pB1 + off); r3 = *(const uint4*)(pB1 + off + 8);
        }
      }
    }
    #pragma unroll
    for (int kk = 0; kk < 64; kk += 32) {
      short8 a = *(short8*)&As[cur][mf][kk + kf];
      #pragma unroll
      for (int j = 0; j < 4; ++j) {
        short8 bfr = *(short8*)&Bs[cur][ncb + j * 16 + l16][kk + kf];
        acc[j] = __builtin_amdgcn_mfma_f32_16x16x32_bf16(a, bfr, acc[j], 0, 0, 0);
      }
    }
    __syncthreads();
  }
  int seg = n0 >> 8;
  const float* bb = (seg == 0 ? bq : (seg == 1 ? bk : bv));
  bf16* dst = (seg == 0 ? qo : (seg == 1 ? ko : vo));
  int row0 = m0 + (w & 3) * 16 + quad * 4;
  #pragma unroll
  for (int j = 0; j < 4; ++j) {
    int col = (n0 & 255) + ncb + j * 16 + l16;
    float bs = bb[col];
    #pragma unroll
    for (int r = 0; r < 4; ++r)
      dst[(size_t)(row0 + r) * 256 + col] = __float2bfloat16(acc[j][r] + bs);
  }
}

// ---------------- uw GEMM: 64x128 tile, 512 thr, BK=64, dbuf; gelu -> bf16 out ----------------
__global__ __launch_bounds__(512) void mgemm_uw2(const bf16* __restrict__ Ab,
    const bf16* __restrict__ Wt, const float* __restrict__ bias,
    bf16* __restrict__ Cb, int N)
{
  __shared__ short As[2][64][72];
  __shared__ short Bs[2][128][72];
  int t = threadIdx.x;
  int m0 = blockIdx.y * 64, n0 = blockIdx.x * 128;
  int w = t >> 6, lane = t & 63;
  int l16 = lane & 15, quad = lane >> 4;
  int s = t & 255;
  int srow = s >> 2, sseg = (s & 3) * 16;
  bool isA = (t < 256);
  const int K = 256;
  const bf16* pA  = Ab + (size_t)(m0 + srow) * K + sseg;
  const bf16* pB0 = Wt + (size_t)(n0 + srow) * K + sseg;
  const bf16* pB1 = Wt + (size_t)(n0 + 64 + srow) * K + sseg;
  uint4 r0, r1, r2, r3;
  if (isA) {
    r0 = *(const uint4*)pA; r1 = *(const uint4*)(pA + 8);
    *(uint4*)&As[0][srow][sseg] = r0; *(uint4*)&As[0][srow][sseg + 8] = r1;
    r0 = *(const uint4*)(pA + 64); r1 = *(const uint4*)(pA + 72);
  } else {
    r0 = *(const uint4*)pB0; r1 = *(const uint4*)(pB0 + 8);
    r2 = *(const uint4*)pB1; r3 = *(const uint4*)(pB1 + 8);
    *(uint4*)&Bs[0][srow][sseg] = r0; *(uint4*)&Bs[0][srow][sseg + 8] = r1;
    *(uint4*)&Bs[0][srow + 64][sseg] = r2; *(uint4*)&Bs[0][srow + 64][sseg + 8] = r3;
    r0 = *(const uint4*)(pB0 + 64); r1 = *(const uint4*)(pB0 + 72);
    r2 = *(const uint4*)(pB1 + 64); r3 = *(const uint4*)(pB1 + 72);
  }
  __syncthreads();
  f32x4 acc[4] = {{0.f,0.f,0.f,0.f},{0.f,0.f,0.f,0.f},{0.f,0.f,0.f,0.f},{0.f,0.f,0.f,0.f}};
  int mf = (w & 3) * 16 + l16;
  int kf = quad * 8;
  int ncb = (w >> 2) * 64;
  const int nsteps = 4;
  for (int i = 0; i < nsteps; ++i) {
    int cur = i & 1;
    if (i + 1 < nsteps) {
      if (isA) {
        *(uint4*)&As[cur ^ 1][srow][sseg] = r0; *(uint4*)&As[cur ^ 1][srow][sseg + 8] = r1;
      } else {
        *(uint4*)&Bs[cur ^ 1][srow][sseg] = r0; *(uint4*)&Bs[cur ^ 1][srow][sseg + 8] = r1;
        *(uint4*)&Bs[cur ^ 1][srow + 64][sseg] = r2; *(uint4*)&Bs[cur ^ 1][srow + 64][sseg + 8] = r3;
      }
      if (i + 2 < nsteps) {
        size_t off = (size_t)(i + 2) * 64;
        if (isA) {
          r0 = *(const uint4*)(pA + off); r1 = *(const uint4*)(pA + off + 8);
        } else {
          r0 = *(const uint4*)(pB0 + off); r1 = *(const uint4*)(pB0 + off + 8);
          r2 = *(const uint4*)(pB1 + off); r3 = *(const uint4*)(pB1 + off + 8);
        }
      }
    }
    #pragma unroll
    for (int kk = 0; kk < 64; kk += 32) {
      short8 a = *(short8*)&As[cur][mf][kk + kf];
      #pragma unroll
      for (int j = 0; j < 4; ++j) {
        short8 bfr = *(short8*)&Bs[cur][ncb + j * 16 + l16][kk + kf];
        acc[j] = __builtin_amdgcn_mfma_f32_16x16x32_bf16(a, bfr, acc[j], 0, 0, 0);
      }
    }
    __syncthreads();
  }
  int row0 = m0 + (w & 3) * 16 + quad * 4;
  #pragma unroll
  for (int j = 0; j < 4; ++j) {
    int col = n0 + ncb + j * 16 + l16;
    float bs = bias[col];
    #pragma unroll
    for (int r = 0; r < 4; ++r) {
      float v = acc[j][r] + bs;
      v = 0.5f * v * (1.0f + erff(v * 0.70710678118654752f));
      Cb[(size_t)(row0 + r) * N + col] = __float2bfloat16(v);
    }
  }
}

// ---------------- MFMA flash attention: K/V LDS double-buffer, depth-2 prefetch ----------------
__global__ __launch_bounds__(256) void k_flash(const bf16* __restrict__ q,
    const bf16* __restrict__ k, const bf16* __restrict__ v, bf16* __restrict__ o)
{
  int qt = blockIdx.x, h = blockIdx.y, b = blockIdx.z;
  int t = threadIdx.x;
  int w = t >> 6, lane = t & 63;
  int quad = lane >> 4, l16 = lane & 15;
  __shared__ short Ks[2][64][40];
  __shared__ short Vt[2][32][76];
  __shared__ short Pl[4][16][72];
  short8 a_q = *(const short8*)&q[((size_t)(b * M_) + qt * 64 + w * 16 + l16) * D_ + h * 32 + quad * 8];
  f32x4 o_acc[2] = {{0.f,0.f,0.f,0.f},{0.f,0.f,0.f,0.f}};
  float l_acc[4] = {0.f, 0.f, 0.f, 0.f};
  int skey = t >> 2, sseg = t & 3;
  const float scale = 0.17677669529663687f;
  const bf16* pk = &k[((size_t)(b * M_) + skey) * D_ + h * 32 + sseg * 8];
  const bf16* pv = &v[((size_t)(b * M_) + skey) * D_ + h * 32 + sseg * 8];
  short8 rk = *(const short8*)pk;
  short8 rv = *(const short8*)pv;
  *(short8*)&Ks[0][skey][sseg * 8] = rk;
  #pragma unroll
  for (int i = 0; i < 8; ++i) Vt[0][sseg * 8 + i][skey] = rv[i];
  rk = *(const short8*)(pk + (size_t)64 * D_);
  rv = *(const short8*)(pv + (size_t)64 * D_);
  __syncthreads();
  for (int kt = 0; kt < 16; ++kt) {
    int cur = kt & 1;
    if (kt < 15) {
      *(short8*)&Ks[cur ^ 1][skey][sseg * 8] = rk;
      #pragma unroll
      for (int i = 0; i < 8; ++i) Vt[cur ^ 1][sseg * 8 + i][skey] = rv[i];
      if (kt < 14) {
        rk = *(const short8*)(pk + (size_t)(kt + 2) * 64 * D_);
        rv = *(const short8*)(pv + (size_t)(kt + 2) * 64 * D_);
      }
    }
    #pragma unroll
    for (int st = 0; st < 4; ++st) {
      short8 bf = *(short8*)&Ks[cur][st * 16 + l16][quad * 8];
      f32x4 s4 = __builtin_amdgcn_mfma_f32_16x16x32_bf16(a_q, bf, (f32x4){0.f,0.f,0.f,0.f}, 0, 0, 0);
      #pragma unroll
      for (int r = 0; r < 4; ++r) {
        float p = __expf(s4[r] * scale);
        l_acc[r] += p;
        bf16 hb = __float2bfloat16(p);
        Pl[w][quad * 4 + r][st * 16 + l16] = *reinterpret_cast<short*>(&hb);
      }
    }
    asm volatile("s_waitcnt lgkmcnt(0)" ::: "memory");
    #pragma unroll
    for (int kh = 0; kh < 2; ++kh) {
      short8 a_p = *(short8*)&Pl[w][l16][kh * 32 + quad * 8];
      #pragma unroll
      for (int nt = 0; nt < 2; ++nt) {
        short8 b_v = *(short8*)&Vt[cur][nt * 16 + l16][kh * 32 + quad * 8];
        o_acc[nt] = __builtin_amdgcn_mfma_f32_16x16x32_bf16(a_p, b_v, o_acc[nt], 0, 0, 0);
      }
    }
    __syncthreads();
  }
  #pragma unroll
  for (int r = 0; r < 4; ++r) {
    float lv = l_acc[r];
    lv += __shfl_xor(lv, 1, 64);
    lv += __shfl_xor(lv, 2, 64);
    lv += __shfl_xor(lv, 4, 64);
    lv += __shfl_xor(lv, 8, 64);
    l_acc[r] = 1.0f / lv;
  }
  #pragma unroll
  for (int nt = 0; nt < 2; ++nt)
    #pragma unroll
    for (int r = 0; r < 4; ++r)
      o[((size_t)(b * M_) + qt * 64 + w * 16 + quad * 4 + r) * D_ + h * 32 + nt * 16 + l16] =
          __float2bfloat16(o_acc[nt][r] * l_acc[r]);
}

// ---------------- fused s head: 8 waves, both triangle tiles in parallel (unchanged) ----------------
__global__ __launch_bounds__(512) void k_shead_f(const bf16* __restrict__ q3,
    const bf16* __restrict__ k3, const float* __restrict__ snw, const float* __restrict__ snb,
    const float* __restrict__ sfw, const float* __restrict__ sfb, float* __restrict__ outs)
{
  int p = blockIdx.x, b = blockIdx.z;
  int it = 0;
  while ((it + 1) * (it + 2) / 2 <= p) ++it;
  int jt = p - it * (it + 1) / 2;
  int t = threadIdx.x;
  int half = t >> 8;          // 0 -> Sa, 1 -> Sb
  int tl = t & 255;
  int w = tl >> 6, lane = tl & 63;
  int quad = lane >> 4, l16 = lane & 15;
  __shared__ float Sa[64][65], Sb[64][65];
  const float scale = 0.17677669529663687f;
  float wsn[H_], bsn[H_], wsf[H_];
  #pragma unroll
  for (int h = 0; h < H_; ++h) { wsn[h] = snw[h]; bsn[h] = snb[h]; wsf[h] = sfw[h]; }
  float bias0 = sfb[0];
  int rt = half ? jt : it;    // q-row tile
  int ct = half ? it : jt;    // k-col tile  (diag: both halves compute identical values)
  float (*S)[65] = half ? Sb : Sa;
  short8 aqs[H_];
  #pragma unroll
  for (int h = 0; h < H_; ++h)
    aqs[h] = *(const short8*)&q3[((size_t)(b * M_) + rt * 64 + w * 16 + l16) * D_ + h * 32 + quad * 8];
  #pragma unroll
  for (int cf = 0; cf < 4; ++cf) {
    f32x4 s4[H_];
    #pragma unroll
    for (int h = 0; h < H_; ++h) {
      short8 bk = *(const short8*)&k3[((size_t)(b * M_) + ct * 64 + cf * 16 + l16) * D_ + h * 32 + quad * 8];
      s4[h] = __builtin_amdgcn_mfma_f32_16x16x32_bf16(aqs[h], bk, (f32x4){0.f,0.f,0.f,0.f}, 0, 0, 0);
    }
    #pragma unroll
    for (int r = 0; r < 4; ++r) {
      float d8[H_], ssum = 0.f, ssq = 0.f;
      #pragma unroll
      for (int h = 0; h < H_; ++h) {
        float s = s4[h][r] * scale;
        d8[h] = s; ssum += s; ssq += s * s;
      }
      float mu = ssum * 0.125f;
      float var = ssq * 0.125f - mu * mu;
      float rstd = rsqrtf(var + 1e-5f);
      float val = bias0;
      #pragma unroll
      for (int h = 0; h < H_; ++h)
        val += ((d8[h] - mu) * rstd * wsn[h] + bsn[h]) * wsf[h];
      S[w * 16 + quad * 4 + r][cf * 16 + l16] = val;
    }
  }
  __syncthreads();
  bool diag = (it == jt);
  int i = tl >> 2, j0 = (tl & 3) * 16;
  if (half == 0) {
    #pragma unroll
    for (int jj = 0; jj < 16; ++jj) {
      int j = j0 + jj;
      outs[((size_t)(b * M_) + it * 64 + i) * M_ + jt * 64 + j] = 0.5f * (Sa[i][j] + Sb[j][i]);
    }
  } else if (!diag) {
    #pragma unroll
    for (int ii = 0; ii < 16; ++ii) {
      int i2 = j0 + ii;
      outs[((size_t)(b * M_) + jt * 64 + i) * M_ + it * 64 + i2] = 0.5f * (Sb[i][i2] + Sa[i2][i]);
    }
  }
}

extern "C" void kernel_launch(void* const* d_in, const int* in_sizes, int n_in,
                              void* d_out, int out_size, void* d_ws, size_t ws_size,
                              hipStream_t stream)
{
  const float* X    = (const float*)d_in[0];
  const float* fW   = (const float*)d_in[2];
  const float* fb   = (const float*)d_in[3];
  const float* cW   = (const float*)d_in[4];
  const float* cb   = (const float*)d_in[5];
  const float* Wq   = (const float*)d_in[6];
  const float* bq   = (const float*)d_in[7];
  const float* Wk   = (const float*)d_in[8];
  const float* bk   = (const float*)d_in[9];
  const float* Wv   = (const float*)d_in[10];
  const float* bv   = (const float*)d_in[11];
  const float* Wo   = (const float*)d_in[12];
  const float* bo   = (const float*)d_in[13];
  const float* ln1w = (const float*)d_in[14];
  const float* ln1b = (const float*)d_in[15];
  const float* ln2w = (const float*)d_in[16];
  const float* ln2b = (const float*)d_in[17];
  const float* lnfw = (const float*)d_in[18];
  const float* lnfb = (const float*)d_in[19];
  const float* uw   = (const float*)d_in[20];
  const float* ub   = (const float*)d_in[21];
  const float* dw   = (const float*)d_in[22];
  const float* db   = (const float*)d_in[23];
  const float* finw = (const float*)d_in[24];
  const float* finb = (const float*)d_in[25];
  const float* snw  = (const float*)d_in[26];
  const float* snb  = (const float*)d_in[27];
  const float* sfw  = (const float*)d_in[28];
  const float* sfb  = (const float*)d_in[29];

  char* base = (char*)d_ws;
  const size_t MiB = 1024 * 1024;
  bf16* q_b   = (bf16*)(base + 0 * MiB);              // layer-3 q lives until s head
  bf16* k_b   = (bf16*)(base + 2 * MiB);              // layer-3 k lives until s head
  bf16* wqkvt = (bf16*)(base + 4 * MiB);              // 1.5 MiB
  bf16* wot   = (bf16*)(base + 5 * MiB + 512 * 1024); // 512 KiB
  bf16* uwt   = (bf16*)(base + 6 * MiB);              // 2 MiB
  bf16* dwt   = (bf16*)(base + 8 * MiB);              // 2 MiB
  bf16* fwt   = (bf16*)(base + 10 * MiB);             // 32 KiB
  float* x    = (float*)(base + 10 * MiB + 512 * 1024); // 4 MiB
  char* SR    = base + 14 * MiB + 512 * 1024;
  bf16* xn_b  = (bf16*)(SR + 0 * MiB);
  bf16* v_b   = (bf16*)(SR + 2 * MiB);
  bf16* att_b = (bf16*)(SR + 4 * MiB);
  bf16* h1_b  = (bf16*)(SR + 6 * MiB);                // 8 MiB
  float* outx = (float*)d_out;
  float* outs = outx + (size_t)BM_TOT * 64;

  dim3 blk(256);
  dim3 blk512(512);
  wconv_embed<<<dim3(772 + BM_TOT / 4), blk, 0, stream>>>(
      Wq, Wk, Wv, Wo, uw, dw, finw, wqkvt, wot, uwt, dwt, fwt,
      X, fW, fb, cW, cb, x);
  for (int l = 0; l < L_; ++l) {
    k_ln<<<dim3(BM_TOT / 4), blk, 0, stream>>>(x, ln1w + l * D_, ln1b + l * D_, xn_b);
    mgemm_qkv2<<<dim3(6, 64), blk512, 0, stream>>>(xn_b, wqkvt + (size_t)l * 196608,
                                                   bq + l * D_, bk + l * D_, bv + l * D_,
                                                   q_b, k_b, v_b);
    k_flash<<<dim3(16, H_, B_), blk, 0, stream>>>(q_b, k_b, v_b, att_b);
    mgemm512<<<dim3(4, 64), blk512, 0, stream>>>(att_b, wot + (size_t)l * 65536, bo + l * D_,
                                                 x, x, nullptr, 256, 256, 2 | 8);
    k_ln<<<dim3(BM_TOT / 4), blk, 0, stream>>>(x, ln2w + l * D_, ln2b + l * D_, xn_b);
    mgemm_uw2<<<dim3(8, 64), blk512, 0, stream>>>(xn_b, uwt + (size_t)l * 262144,
                                                  ub + l * DFF_, h1_b, 1024);
    mgemm512<<<dim3(4, 64), blk512, 0, stream>>>(h1_b, dwt + (size_t)l * 262144, db + l * D_,
                                                 x, x, nullptr, 1024, 256, 2 | 8);
  }
  k_ln<<<dim3(BM_TOT / 4), blk, 0, stream>>>(x, lnfw, lnfb, xn_b);
  mgemm512<<<dim3(1, 64), blk512, 0, stream>>>(xn_b, fwt, finb, nullptr, outx, nullptr, 256, 64, 8);
  // layer-3 q/k still live in q_b/k_b
  k_shead_f<<<dim3(136, 1, B_), blk512, 0, stream>>>(q_b, k_b, snw, snb, sfw, sfb, outs);
}

// Round 11
// 390.961 us; speedup vs baseline: 1.2178x; 1.0232x over previous
//
#include <hip/hip_runtime.h>
#include <hip/hip_bf16.h>
#include <math.h>

#define B_ 4
#define M_ 1024
#define NIN 70
#define D_ 256
#define H_ 8
#define L_ 4
#define DFF_ 1024
#define BM_TOT 4096

typedef __hip_bfloat16 bf16;
typedef short short8 __attribute__((ext_vector_type(8)));
typedef float f32x4 __attribute__((ext_vector_type(4)));

// ---------------- merged: weight convert+transpose (idx<772) | embedding (idx>=772) ----------------
__global__ __launch_bounds__(256) void wconv_embed(
    const float* __restrict__ Wq, const float* __restrict__ Wk, const float* __restrict__ Wv,
    const float* __restrict__ Wo, const float* __restrict__ uw, const float* __restrict__ dw,
    const float* __restrict__ finw,
    bf16* __restrict__ wqkvt, bf16* __restrict__ wot, bf16* __restrict__ uwt,
    bf16* __restrict__ dwt, bf16* __restrict__ fwt,
    const float* __restrict__ X, const float* __restrict__ fW, const float* __restrict__ fb,
    const float* __restrict__ cW, const float* __restrict__ cb, float* __restrict__ x)
{
  __shared__ float T[64][65];
  __shared__ float xr[4][NIN];
  int idx = blockIdx.x;
  int t = threadIdx.x;
  if (idx >= 772) {
    // ---- embedding: 4 rows/block ----
    int bm0 = (idx - 772) * 4;
    int d = t;
    for (int i = d; i < 4 * NIN; i += 256)
      xr[i / NIN][i % NIN] = X[(size_t)(bm0 + i / NIN) * NIN + i % NIN];
    __syncthreads();
    int f = d & 127;
    float fw0 = fW[f * 3 + 0], fw1 = fW[f * 3 + 1], fw2 = fW[f * 3 + 2], fbv = fb[f];
    float cbv = cb[d];
    float acc[4];
    #pragma unroll
    for (int r = 0; r < 4; ++r) {
      float proj = xr[r][0] * fw0 + xr[r][1] * fw1 + xr[r][2] * fw2 + fbv;
      acc[r] = (d < 128 ? cosf(proj) : sinf(proj)) * 0.17677669529663687f + cbv;
    }
    #pragma unroll 8
    for (int c = 0; c < 64; ++c) {
      float cw = cW[c * D_ + d];
      #pragma unroll
      for (int r = 0; r < 4; ++r) acc[r] += xr[r][6 + c] * cw;
    }
    #pragma unroll
    for (int r = 0; r < 4; ++r)
      x[(size_t)(bm0 + r) * D_ + d] = acc[r];
    return;
  }
  // ---- weight convert ----
  const float* src; bf16* dst; int K, N, k0, n0, rbase, S;
  if (idx < 192) {            // Wq/Wk/Wv -> wqkvt[l][m*256 + n][k]
    int m = idx >> 6; int r = idx & 63; int l = r >> 4; int tt = r & 15;
    int kt = tt >> 2, nt = tt & 3;
    src = (m == 0 ? Wq : (m == 1 ? Wk : Wv)) + (size_t)l * 65536;
    K = 256; N = 256; k0 = kt * 64; n0 = nt * 64;
    dst = wqkvt + (size_t)l * 196608; rbase = m * 256 + nt * 64; S = 256;
  } else if (idx < 256) {     // Wo
    int r = idx - 192; int l = r >> 4; int tt = r & 15; int kt = tt >> 2, nt = tt & 3;
    src = Wo + (size_t)l * 65536; K = 256; N = 256; k0 = kt * 64; n0 = nt * 64;
    dst = wot + (size_t)l * 65536; rbase = nt * 64; S = 256;
  } else if (idx < 512) {     // uw (256 x 1024)
    int r = idx - 256; int l = r >> 6; int tt = r & 63; int kt = tt >> 4, nt = tt & 15;
    src = uw + (size_t)l * 262144; K = 256; N = 1024; k0 = kt * 64; n0 = nt * 64;
    dst = uwt + (size_t)l * 262144; rbase = nt * 64; S = 256;
  } else if (idx < 768) {     // dw (1024 x 256)
    int r = idx - 512; int l = r >> 6; int tt = r & 63; int kt = tt >> 2, nt = tt & 3;
    src = dw + (size_t)l * 262144; K = 1024; N = 256; k0 = kt * 64; n0 = nt * 64;
    dst = dwt + (size_t)l * 262144; rbase = nt * 64; S = 1024;
  } else {                    // finw (256 x 64)
    int kt = idx - 768;
    src = finw; K = 256; N = 64; k0 = kt * 64; n0 = 0;
    dst = fwt; rbase = 0; S = 256;
  }
  int kl = t >> 2, ns = (t & 3) * 16;
  #pragma unroll
  for (int i = 0; i < 16; i += 4)
    *(float4*)&T[kl][ns + i] = *(const float4*)&src[(size_t)(k0 + kl) * N + n0 + ns + i];
  __syncthreads();
  int nl = t >> 2, ks = (t & 3) * 16;
  __align__(16) bf16 tmp[16];
  #pragma unroll
  for (int i = 0; i < 16; ++i) tmp[i] = __float2bfloat16(T[ks + i][nl]);
  *(uint4*)&dst[(size_t)(rbase + nl) * S + k0 + ks] = *(uint4*)&tmp[0];
  *(uint4*)&dst[(size_t)(rbase + nl) * S + k0 + ks + 8] = *(uint4*)&tmp[8];
}

// ---------------- layernorm: fp32 in -> bf16 out ----------------
__global__ __launch_bounds__(256) void k_ln(const float* __restrict__ xin,
    const float* __restrict__ w, const float* __restrict__ b, bf16* __restrict__ xout)
{
  int wave = threadIdx.x >> 6;
  int lane = threadIdx.x & 63;
  int row = blockIdx.x * 4 + wave;
  float4 xv = *(const float4*)&xin[row * D_ + lane * 4];
  float s = xv.x + xv.y + xv.z + xv.w;
  float q = xv.x * xv.x + xv.y * xv.y + xv.z * xv.z + xv.w * xv.w;
  #pragma unroll
  for (int off = 32; off; off >>= 1) {
    s += __shfl_xor(s, off, 64);
    q += __shfl_xor(q, off, 64);
  }
  float mu = s * (1.0f / D_);
  float var = q * (1.0f / D_) - mu * mu;
  float rstd = rsqrtf(var + 1e-5f);
  float4 wv = *(const float4*)&w[lane * 4];
  float4 bv = *(const float4*)&b[lane * 4];
  __align__(8) bf16 tmp[4];
  tmp[0] = __float2bfloat16((xv.x - mu) * rstd * wv.x + bv.x);
  tmp[1] = __float2bfloat16((xv.y - mu) * rstd * wv.y + bv.y);
  tmp[2] = __float2bfloat16((xv.z - mu) * rstd * wv.z + bv.z);
  tmp[3] = __float2bfloat16((xv.w - mu) * rstd * wv.w + bv.w);
  *(uint2*)&xout[row * D_ + lane * 4] = *(uint2*)tmp;
}

// ---------------- MFMA GEMM, 512 thr / 8 waves, BK=64, LDS double-buffer (64x64 tile) ----------------
__global__ __launch_bounds__(512) void mgemm512(const bf16* __restrict__ Ab,
    const bf16* __restrict__ Wt, const float* __restrict__ bias,
    const float* __restrict__ Res, float* __restrict__ Cf, bf16* __restrict__ Cb,
    int K, int N, int flags)
{
  __shared__ short As[2][64][72];
  __shared__ short Bs[2][64][72];
  int t = threadIdx.x;
  int m0 = blockIdx.y * 64, n0 = blockIdx.x * 64;
  int w = t >> 6, lane = t & 63;
  int l16 = lane & 15, quad = lane >> 4;
  int s = t & 255;
  int srow = s >> 2, sseg = (s & 3) * 16;
  bool isA = (t < 256);
  const bf16* pS = (isA ? Ab + (size_t)(m0 + srow) * K
                        : Wt + (size_t)(n0 + srow) * K) + sseg;
  uint4 ra0 = *(const uint4*)pS, ra1 = *(const uint4*)(pS + 8);
  {
    short (*S)[72] = isA ? As[0] : Bs[0];
    *(uint4*)&S[srow][sseg] = ra0;
    *(uint4*)&S[srow][sseg + 8] = ra1;
  }
  int nsteps = K >> 6;
  if (nsteps > 1) {
    ra0 = *(const uint4*)(pS + 64);
    ra1 = *(const uint4*)(pS + 72);
  }
  __syncthreads();
  f32x4 acc[2] = {{0.f,0.f,0.f,0.f},{0.f,0.f,0.f,0.f}};
  int mf = (w & 3) * 16 + l16;
  int kf = quad * 8;
  int ntb = (w >> 2) * 2;
  for (int i = 0; i < nsteps; ++i) {
    int cur = i & 1;
    if (i + 1 < nsteps) {
      short (*S)[72] = isA ? As[cur ^ 1] : Bs[cur ^ 1];
      *(uint4*)&S[srow][sseg] = ra0;
      *(uint4*)&S[srow][sseg + 8] = ra1;
      if (i + 2 < nsteps) {
        ra0 = *(const uint4*)(pS + (size_t)(i + 2) * 64);
        ra1 = *(const uint4*)(pS + (size_t)(i + 2) * 64 + 8);
      }
    }
    #pragma unroll
    for (int kk = 0; kk < 64; kk += 32) {
      short8 a = *(short8*)&As[cur][mf][kk + kf];
      #pragma unroll
      for (int j = 0; j < 2; ++j) {
        short8 bfr = *(short8*)&Bs[cur][(ntb + j) * 16 + l16][kk + kf];
        acc[j] = __builtin_amdgcn_mfma_f32_16x16x32_bf16(a, bfr, acc[j], 0, 0, 0);
      }
    }
    __syncthreads();
  }
  int row0 = m0 + (w & 3) * 16 + quad * 4;
  #pragma unroll
  for (int j = 0; j < 2; ++j) {
    int col = n0 + (ntb + j) * 16 + l16;
    float bs = bias[col];
    #pragma unroll
    for (int r = 0; r < 4; ++r) {
      float v = acc[j][r] + bs;
      if (flags & 1) v = 0.5f * v * (1.0f + erff(v * 0.70710678118654752f));
      if (flags & 2) v += Res[(size_t)(row0 + r) * N + col];
      if (flags & 8) Cf[(size_t)(row0 + r) * N + col] = v;
      if (flags & 4) Cb[(size_t)(row0 + r) * N + col] = __float2bfloat16(v);
    }
  }
}

// ---------------- QKV GEMM: 64x128 tile, 512 thr, BK=64, dbuf, depth-2 prefetch ----------------
__global__ __launch_bounds__(512) void mgemm_qkv2(const bf16* __restrict__ Ab,
    const bf16* __restrict__ Wt, const float* __restrict__ bq,
    const float* __restrict__ bk, const float* __restrict__ bv,
    bf16* __restrict__ qo, bf16* __restrict__ ko, bf16* __restrict__ vo)
{
  __shared__ short As[2][64][72];
  __shared__ short Bs[2][128][72];
  int t = threadIdx.x;
  int m0 = blockIdx.y * 64, n0 = blockIdx.x * 128;
  int w = t >> 6, lane = t & 63;
  int l16 = lane & 15, quad = lane >> 4;
  int s = t & 255;
  int srow = s >> 2, sseg = (s & 3) * 16;
  bool isA = (t < 256);
  const int K = 256;
  const bf16* pA  = Ab + (size_t)(m0 + srow) * K + sseg;
  const bf16* pB0 = Wt + (size_t)(n0 + srow) * K + sseg;
  const bf16* pB1 = Wt + (size_t)(n0 + 64 + srow) * K + sseg;
  uint4 r0, r1, r2, r3;
  if (isA) {
    r0 = *(const uint4*)pA; r1 = *(const uint4*)(pA + 8);
    *(uint4*)&As[0][srow][sseg] = r0; *(uint4*)&As[0][srow][sseg + 8] = r1;
    r0 = *(const uint4*)(pA + 64); r1 = *(const uint4*)(pA + 72);
  } else {
    r0 = *(const uint4*)pB0; r1 = *(const uint4*)(pB0 + 8);
    r2 = *(const uint4*)pB1; r3 = *(const uint4*)(pB1 + 8);
    *(uint4*)&Bs[0][srow][sseg] = r0; *(uint4*)&Bs[0][srow][sseg + 8] = r1;
    *(uint4*)&Bs[0][srow + 64][sseg] = r2; *(uint4*)&Bs[0][srow + 64][sseg + 8] = r3;
    r0 = *(const uint4*)(pB0 + 64); r1 = *(const uint4*)(pB0 + 72);
    r2 = *(const uint4*)(pB1 + 64); r3 = *(const uint4*)(pB1 + 72);
  }
  __syncthreads();
  f32x4 acc[4] = {{0.f,0.f,0.f,0.f},{0.f,0.f,0.f,0.f},{0.f,0.f,0.f,0.f},{0.f,0.f,0.f,0.f}};
  int mf = (w & 3) * 16 + l16;
  int kf = quad * 8;
  int ncb = (w >> 2) * 64;
  const int nsteps = 4;
  for (int i = 0; i < nsteps; ++i) {
    int cur = i & 1;
    if (i + 1 < nsteps) {
      if (isA) {
        *(uint4*)&As[cur ^ 1][srow][sseg] = r0; *(uint4*)&As[cur ^ 1][srow][sseg + 8] = r1;
      } else {
        *(uint4*)&Bs[cur ^ 1][srow][sseg] = r0; *(uint4*)&Bs[cur ^ 1][srow][sseg + 8] = r1;
        *(uint4*)&Bs[cur ^ 1][srow + 64][sseg] = r2; *(uint4*)&Bs[cur ^ 1][srow + 64][sseg + 8] = r3;
      }
      if (i + 2 < nsteps) {
        size_t off = (size_t)(i + 2) * 64;
        if (isA) {
          r0 = *(const uint4*)(pA + off); r1 = *(const uint4*)(pA + off + 8);
        } else {
          r0 = *(const uint4*)(pB0 + off); r1 = *(const uint4*)(pB0 + off + 8);
          r2 = *(const uint4*)(pB1 + off); r3 = *(const uint4*)(pB1 + off + 8);
        }
      }
    }
    #pragma unroll
    for (int kk = 0; kk < 64; kk += 32) {
      short8 a = *(short8*)&As[cur][mf][kk + kf];
      #pragma unroll
      for (int j = 0; j < 4; ++j) {
        short8 bfr = *(short8*)&Bs[cur][ncb + j * 16 + l16][kk + kf];
        acc[j] = __builtin_amdgcn_mfma_f32_16x16x32_bf16(a, bfr, acc[j], 0, 0, 0);
      }
    }
    __syncthreads();
  }
  int seg = n0 >> 8;
  const float* bb = (seg == 0 ? bq : (seg == 1 ? bk : bv));
  bf16* dst = (seg == 0 ? qo : (seg == 1 ? ko : vo));
  int row0 = m0 + (w & 3) * 16 + quad * 4;
  #pragma unroll
  for (int j = 0; j < 4; ++j) {
    int col = (n0 & 255) + ncb + j * 16 + l16;
    float bs = bb[col];
    #pragma unroll
    for (int r = 0; r < 4; ++r)
      dst[(size_t)(row0 + r) * 256 + col] = __float2bfloat16(acc[j][r] + bs);
  }
}

// ---------------- uw GEMM: 64x128 tile, 512 thr, BK=64, dbuf; gelu -> bf16 out ----------------
__global__ __launch_bounds__(512) void mgemm_uw2(const bf16* __restrict__ Ab,
    const bf16* __restrict__ Wt, const float* __restrict__ bias,
    bf16* __restrict__ Cb, int N)
{
  __shared__ short As[2][64][72];
  __shared__ short Bs[2][128][72];
  int t = threadIdx.x;
  int m0 = blockIdx.y * 64, n0 = blockIdx.x * 128;
  int w = t >> 6, lane = t & 63;
  int l16 = lane & 15, quad = lane >> 4;
  int s = t & 255;
  int srow = s >> 2, sseg = (s & 3) * 16;
  bool isA = (t < 256);
  const int K = 256;
  const bf16* pA  = Ab + (size_t)(m0 + srow) * K + sseg;
  const bf16* pB0 = Wt + (size_t)(n0 + srow) * K + sseg;
  const bf16* pB1 = Wt + (size_t)(n0 + 64 + srow) * K + sseg;
  uint4 r0, r1, r2, r3;
  if (isA) {
    r0 = *(const uint4*)pA; r1 = *(const uint4*)(pA + 8);
    *(uint4*)&As[0][srow][sseg] = r0; *(uint4*)&As[0][srow][sseg + 8] = r1;
    r0 = *(const uint4*)(pA + 64); r1 = *(const uint4*)(pA + 72);
  } else {
    r0 = *(const uint4*)pB0; r1 = *(const uint4*)(pB0 + 8);
    r2 = *(const uint4*)pB1; r3 = *(const uint4*)(pB1 + 8);
    *(uint4*)&Bs[0][srow][sseg] = r0; *(uint4*)&Bs[0][srow][sseg + 8] = r1;
    *(uint4*)&Bs[0][srow + 64][sseg] = r2; *(uint4*)&Bs[0][srow + 64][sseg + 8] = r3;
    r0 = *(const uint4*)(pB0 + 64); r1 = *(const uint4*)(pB0 + 72);
    r2 = *(const uint4*)(pB1 + 64); r3 = *(const uint4*)(pB1 + 72);
  }
  __syncthreads();
  f32x4 acc[4] = {{0.f,0.f,0.f,0.f},{0.f,0.f,0.f,0.f},{0.f,0.f,0.f,0.f},{0.f,0.f,0.f,0.f}};
  int mf = (w & 3) * 16 + l16;
  int kf = quad * 8;
  int ncb = (w >> 2) * 64;
  const int nsteps = 4;
  for (int i = 0; i < nsteps; ++i) {
    int cur = i & 1;
    if (i + 1 < nsteps) {
      if (isA) {
        *(uint4*)&As[cur ^ 1][srow][sseg] = r0; *(uint4*)&As[cur ^ 1][srow][sseg + 8] = r1;
      } else {
        *(uint4*)&Bs[cur ^ 1][srow][sseg] = r0; *(uint4*)&Bs[cur ^ 1][srow][sseg + 8] = r1;
        *(uint4*)&Bs[cur ^ 1][srow + 64][sseg] = r2; *(uint4*)&Bs[cur ^ 1][srow + 64][sseg + 8] = r3;
      }
      if (i + 2 < nsteps) {
        size_t off = (size_t)(i + 2) * 64;
        if (isA) {
          r0 = *(const uint4*)(pA + off); r1 = *(const uint4*)(pA + off + 8);
        } else {
          r0 = *(const uint4*)(pB0 + off); r1 = *(const uint4*)(pB0 + off + 8);
          r2 = *(const uint4*)(pB1 + off); r3 = *(const uint4*)(pB1 + off + 8);
        }
      }
    }
    #pragma unroll
    for (int kk = 0; kk < 64; kk += 32) {
      short8 a = *(short8*)&As[cur][mf][kk + kf];
      #pragma unroll
      for (int j = 0; j < 4; ++j) {
        short8 bfr = *(short8*)&Bs[cur][ncb + j * 16 + l16][kk + kf];
        acc[j] = __builtin_amdgcn_mfma_f32_16x16x32_bf16(a, bfr, acc[j], 0, 0, 0);
      }
    }
    __syncthreads();
  }
  int row0 = m0 + (w & 3) * 16 + quad * 4;
  #pragma unroll
  for (int j = 0; j < 4; ++j) {
    int col = n0 + ncb + j * 16 + l16;
    float bs = bias[col];
    #pragma unroll
    for (int r = 0; r < 4; ++r) {
      float v = acc[j][r] + bs;
      v = 0.5f * v * (1.0f + erff(v * 0.70710678118654752f));
      Cb[(size_t)(row0 + r) * N + col] = __float2bfloat16(v);
    }
  }
}

// ---------------- MFMA flash attention: 512 thr, 2 q-tiles/block, shared K/V staging ----------------
// Waves 0-3 -> qt = 2*blockIdx.x, waves 4-7 -> qt+1. K/V staged once per block
// (t<256 stage K rows, t>=256 stage V transposed), LDS double-buffer, depth-2 prefetch.
// Per-wave arithmetic identical to the 256-thr version -> bit-identical output.
__global__ __launch_bounds__(512) void k_flash(const bf16* __restrict__ q,
    const bf16* __restrict__ k, const bf16* __restrict__ v, bf16* __restrict__ o)
{
  int qp = blockIdx.x, h = blockIdx.y, b = blockIdx.z;
  int t = threadIdx.x;
  int w = t >> 6, lane = t & 63;
  int quad = lane >> 4, l16 = lane & 15;
  __shared__ short Ks[2][64][40];
  __shared__ short Vt[2][32][76];
  __shared__ short Pl[8][16][72];
  int qt = qp * 2 + (w >> 2);
  short8 a_q = *(const short8*)&q[((size_t)(b * M_) + qt * 64 + (w & 3) * 16 + l16) * D_ + h * 32 + quad * 8];
  f32x4 o_acc[2] = {{0.f,0.f,0.f,0.f},{0.f,0.f,0.f,0.f}};
  float l_acc[4] = {0.f, 0.f, 0.f, 0.f};
  int s = t & 255;
  int skey = s >> 2, sseg = s & 3;
  bool isK = (t < 256);
  const float scale = 0.17677669529663687f;
  const bf16* ps = (isK ? &k[((size_t)(b * M_) + skey) * D_]
                        : &v[((size_t)(b * M_) + skey) * D_]) + h * 32 + sseg * 8;
  short8 rr = *(const short8*)ps;
  if (isK) {
    *(short8*)&Ks[0][skey][sseg * 8] = rr;
  } else {
    #pragma unroll
    for (int i = 0; i < 8; ++i) Vt[0][sseg * 8 + i][skey] = rr[i];
  }
  rr = *(const short8*)(ps + (size_t)64 * D_);
  __syncthreads();
  for (int kt = 0; kt < 16; ++kt) {
    int cur = kt & 1;
    if (kt < 15) {
      if (isK) {
        *(short8*)&Ks[cur ^ 1][skey][sseg * 8] = rr;
      } else {
        #pragma unroll
        for (int i = 0; i < 8; ++i) Vt[cur ^ 1][sseg * 8 + i][skey] = rr[i];
      }
      if (kt < 14)
        rr = *(const short8*)(ps + (size_t)(kt + 2) * 64 * D_);
    }
    #pragma unroll
    for (int st = 0; st < 4; ++st) {
      short8 bf = *(short8*)&Ks[cur][st * 16 + l16][quad * 8];
      f32x4 s4 = __builtin_amdgcn_mfma_f32_16x16x32_bf16(a_q, bf, (f32x4){0.f,0.f,0.f,0.f}, 0, 0, 0);
      #pragma unroll
      for (int r = 0; r < 4; ++r) {
        float p = __expf(s4[r] * scale);
        l_acc[r] += p;
        bf16 hb = __float2bfloat16(p);
        Pl[w][quad * 4 + r][st * 16 + l16] = *reinterpret_cast<short*>(&hb);
      }
    }
    asm volatile("s_waitcnt lgkmcnt(0)" ::: "memory");
    #pragma unroll
    for (int kh = 0; kh < 2; ++kh) {
      short8 a_p = *(short8*)&Pl[w][l16][kh * 32 + quad * 8];
      #pragma unroll
      for (int nt = 0; nt < 2; ++nt) {
        short8 b_v = *(short8*)&Vt[cur][nt * 16 + l16][kh * 32 + quad * 8];
        o_acc[nt] = __builtin_amdgcn_mfma_f32_16x16x32_bf16(a_p, b_v, o_acc[nt], 0, 0, 0);
      }
    }
    __syncthreads();
  }
  #pragma unroll
  for (int r = 0; r < 4; ++r) {
    float lv = l_acc[r];
    lv += __shfl_xor(lv, 1, 64);
    lv += __shfl_xor(lv, 2, 64);
    lv += __shfl_xor(lv, 4, 64);
    lv += __shfl_xor(lv, 8, 64);
    l_acc[r] = 1.0f / lv;
  }
  #pragma unroll
  for (int nt = 0; nt < 2; ++nt)
    #pragma unroll
    for (int r = 0; r < 4; ++r)
      o[((size_t)(b * M_) + qt * 64 + (w & 3) * 16 + quad * 4 + r) * D_ + h * 32 + nt * 16 + l16] =
          __float2bfloat16(o_acc[nt][r] * l_acc[r]);
}

// ---------------- merged tail: shead (blocks 0..543) | final projection (544..607) ----------------
// Both paths 512 threads; LDS overlaid (max 36.9 KB). Independent workloads share one launch.
__global__ __launch_bounds__(512) void k_tail(const bf16* __restrict__ xn,
    const bf16* __restrict__ fwt, const float* __restrict__ finb, float* __restrict__ outx,
    const bf16* __restrict__ q3, const bf16* __restrict__ k3,
    const float* __restrict__ snw, const float* __restrict__ snb,
    const float* __restrict__ sfw, const float* __restrict__ sfb, float* __restrict__ outs)
{
  __shared__ __align__(16) char smem[36864];
  int t = threadIdx.x;
  if (blockIdx.x >= 544) {
    // ---- final projection: 64x64 tile, K=256, N=64, dbuf (mgemm512 body) ----
    short (*As)[64][72] = (short (*)[64][72])smem;
    short (*Bs)[64][72] = (short (*)[64][72])(smem + 18432);
    int m0 = (blockIdx.x - 544) * 64;
    int w = t >> 6, lane = t & 63;
    int l16 = lane & 15, quad = lane >> 4;
    int s = t & 255;
    int srow = s >> 2, sseg = (s & 3) * 16;
    bool isA = (t < 256);
    const bf16* pS = (isA ? xn + (size_t)(m0 + srow) * 256
                          : fwt + (size_t)srow * 256) + sseg;
    uint4 ra0 = *(const uint4*)pS, ra1 = *(const uint4*)(pS + 8);
    {
      short (*S)[72] = isA ? As[0] : Bs[0];
      *(uint4*)&S[srow][sseg] = ra0;
      *(uint4*)&S[srow][sseg + 8] = ra1;
    }
    ra0 = *(const uint4*)(pS + 64);
    ra1 = *(const uint4*)(pS + 72);
    __syncthreads();
    f32x4 acc[2] = {{0.f,0.f,0.f,0.f},{0.f,0.f,0.f,0.f}};
    int mf = (w & 3) * 16 + l16;
    int kf = quad * 8;
    int ntb = (w >> 2) * 2;
    const int nsteps = 4;
    for (int i = 0; i < nsteps; ++i) {
      int cur = i & 1;
      if (i + 1 < nsteps) {
        short (*S)[72] = isA ? As[cur ^ 1] : Bs[cur ^ 1];
        *(uint4*)&S[srow][sseg] = ra0;
        *(uint4*)&S[srow][sseg + 8] = ra1;
        if (i + 2 < nsteps) {
          ra0 = *(const uint4*)(pS + (size_t)(i + 2) * 64);
          ra1 = *(const uint4*)(pS + (size_t)(i + 2) * 64 + 8);
        }
      }
      #pragma unroll
      for (int kk = 0; kk < 64; kk += 32) {
        short8 a = *(short8*)&As[cur][mf][kk + kf];
        #pragma unroll
        for (int j = 0; j < 2; ++j) {
          short8 bfr = *(short8*)&Bs[cur][(ntb + j) * 16 + l16][kk + kf];
          acc[j] = __builtin_amdgcn_mfma_f32_16x16x32_bf16(a, bfr, acc[j], 0, 0, 0);
        }
      }
      __syncthreads();
    }
    int row0 = m0 + (w & 3) * 16 + quad * 4;
    #pragma unroll
    for (int j = 0; j < 2; ++j) {
      int col = (ntb + j) * 16 + l16;
      float bs = finb[col];
      #pragma unroll
      for (int r = 0; r < 4; ++r)
        outx[(size_t)(row0 + r) * 64 + col] = acc[j][r] + bs;
    }
    return;
  }
  // ---- s head: 8 waves, both triangle tiles in parallel ----
  float (*Sa)[65] = (float (*)[65])smem;
  float (*Sb)[65] = (float (*)[65])(smem + 16640);
  int p = blockIdx.x % 136, b = blockIdx.x / 136;
  int it = 0;
  while ((it + 1) * (it + 2) / 2 <= p) ++it;
  int jt = p - it * (it + 1) / 2;
  int half = t >> 8;
  int tl = t & 255;
  int w = tl >> 6, lane = tl & 63;
  int quad = lane >> 4, l16 = lane & 15;
  const float scale = 0.17677669529663687f;
  float wsn[H_], bsn[H_], wsf[H_];
  #pragma unroll
  for (int h = 0; h < H_; ++h) { wsn[h] = snw[h]; bsn[h] = snb[h]; wsf[h] = sfw[h]; }
  float bias0 = sfb[0];
  int rt = half ? jt : it;
  int ct = half ? it : jt;
  float (*S)[65] = half ? Sb : Sa;
  short8 aqs[H_];
  #pragma unroll
  for (int h = 0; h < H_; ++h)
    aqs[h] = *(const short8*)&q3[((size_t)(b * M_) + rt * 64 + w * 16 + l16) * D_ + h * 32 + quad * 8];
  #pragma unroll
  for (int cf = 0; cf < 4; ++cf) {
    f32x4 s4[H_];
    #pragma unroll
    for (int h = 0; h < H_; ++h) {
      short8 bk = *(const short8*)&k3[((size_t)(b * M_) + ct * 64 + cf * 16 + l16) * D_ + h * 32 + quad * 8];
      s4[h] = __builtin_amdgcn_mfma_f32_16x16x32_bf16(aqs[h], bk, (f32x4){0.f,0.f,0.f,0.f}, 0, 0, 0);
    }
    #pragma unroll
    for (int r = 0; r < 4; ++r) {
      float d8[H_], ssum = 0.f, ssq = 0.f;
      #pragma unroll
      for (int h = 0; h < H_; ++h) {
        float sv = s4[h][r] * scale;
        d8[h] = sv; ssum += sv; ssq += sv * sv;
      }
      float mu = ssum * 0.125f;
      float var = ssq * 0.125f - mu * mu;
      float rstd = rsqrtf(var + 1e-5f);
      float val = bias0;
      #pragma unroll
      for (int h = 0; h < H_; ++h)
        val += ((d8[h] - mu) * rstd * wsn[h] + bsn[h]) * wsf[h];
      S[w * 16 + quad * 4 + r][cf * 16 + l16] = val;
    }
  }
  __syncthreads();
  bool diag = (it == jt);
  int i = tl >> 2, j0 = (tl & 3) * 16;
  if (half == 0) {
    #pragma unroll
    for (int jj = 0; jj < 16; ++jj) {
      int j = j0 + jj;
      outs[((size_t)(b * M_) + it * 64 + i) * M_ + jt * 64 + j] = 0.5f * (Sa[i][j] + Sb[j][i]);
    }
  } else if (!diag) {
    #pragma unroll
    for (int ii = 0; ii < 16; ++ii) {
      int i2 = j0 + ii;
      outs[((size_t)(b * M_) + jt * 64 + i) * M_ + it * 64 + i2] = 0.5f * (Sb[i][i2] + Sa[i2][i]);
    }
  }
}

extern "C" void kernel_launch(void* const* d_in, const int* in_sizes, int n_in,
                              void* d_out, int out_size, void* d_ws, size_t ws_size,
                              hipStream_t stream)
{
  const float* X    = (const float*)d_in[0];
  const float* fW   = (const float*)d_in[2];
  const float* fb   = (const float*)d_in[3];
  const float* cW   = (const float*)d_in[4];
  const float* cb   = (const float*)d_in[5];
  const float* Wq   = (const float*)d_in[6];
  const float* bq   = (const float*)d_in[7];
  const float* Wk   = (const float*)d_in[8];
  const float* bk   = (const float*)d_in[9];
  const float* Wv   = (const float*)d_in[10];
  const float* bv   = (const float*)d_in[11];
  const float* Wo   = (const float*)d_in[12];
  const float* bo   = (const float*)d_in[13];
  const float* ln1w = (const float*)d_in[14];
  const float* ln1b = (const float*)d_in[15];
  const float* ln2w = (const float*)d_in[16];
  const float* ln2b = (const float*)d_in[17];
  const float* lnfw = (const float*)d_in[18];
  const float* lnfb = (const float*)d_in[19];
  const float* uw   = (const float*)d_in[20];
  const float* ub   = (const float*)d_in[21];
  const float* dw   = (const float*)d_in[22];
  const float* db   = (const float*)d_in[23];
  const float* finw = (const float*)d_in[24];
  const float* finb = (const float*)d_in[25];
  const float* snw  = (const float*)d_in[26];
  const float* snb  = (const float*)d_in[27];
  const float* sfw  = (const float*)d_in[28];
  const float* sfb  = (const float*)d_in[29];

  char* base = (char*)d_ws;
  const size_t MiB = 1024 * 1024;
  bf16* q_b   = (bf16*)(base + 0 * MiB);              // layer-3 q lives until s head
  bf16* k_b   = (bf16*)(base + 2 * MiB);              // layer-3 k lives until s head
  bf16* wqkvt = (bf16*)(base + 4 * MiB);              // 1.5 MiB
  bf16* wot   = (bf16*)(base + 5 * MiB + 512 * 1024); // 512 KiB
  bf16* uwt   = (bf16*)(base + 6 * MiB);              // 2 MiB
  bf16* dwt   = (bf16*)(base + 8 * MiB);              // 2 MiB
  bf16* fwt   = (bf16*)(base + 10 * MiB);             // 32 KiB
  float* x    = (float*)(base + 10 * MiB + 512 * 1024); // 4 MiB
  char* SR    = base + 14 * MiB + 512 * 1024;
  bf16* xn_b  = (bf16*)(SR + 0 * MiB);
  bf16* v_b   = (bf16*)(SR + 2 * MiB);
  bf16* att_b = (bf16*)(SR + 4 * MiB);
  bf16* h1_b  = (bf16*)(SR + 6 * MiB);                // 8 MiB
  float* outx = (float*)d_out;
  float* outs = outx + (size_t)BM_TOT * 64;

  dim3 blk(256);
  dim3 blk512(512);
  wconv_embed<<<dim3(772 + BM_TOT / 4), blk, 0, stream>>>(
      Wq, Wk, Wv, Wo, uw, dw, finw, wqkvt, wot, uwt, dwt, fwt,
      X, fW, fb, cW, cb, x);
  for (int l = 0; l < L_; ++l) {
    k_ln<<<dim3(BM_TOT / 4), blk, 0, stream>>>(x, ln1w + l * D_, ln1b + l * D_, xn_b);
    mgemm_qkv2<<<dim3(6, 64), blk512, 0, stream>>>(xn_b, wqkvt + (size_t)l * 196608,
                                                   bq + l * D_, bk + l * D_, bv + l * D_,
                                                   q_b, k_b, v_b);
    k_flash<<<dim3(8, H_, B_), blk512, 0, stream>>>(q_b, k_b, v_b, att_b);
    mgemm512<<<dim3(4, 64), blk512, 0, stream>>>(att_b, wot + (size_t)l * 65536, bo + l * D_,
                                                 x, x, nullptr, 256, 256, 2 | 8);
    k_ln<<<dim3(BM_TOT / 4), blk, 0, stream>>>(x, ln2w + l * D_, ln2b + l * D_, xn_b);
    mgemm_uw2<<<dim3(8, 64), blk512, 0, stream>>>(xn_b, uwt + (size_t)l * 262144,
                                                  ub + l * DFF_, h1_b, 1024);
    mgemm512<<<dim3(4, 64), blk512, 0, stream>>>(h1_b, dwt + (size_t)l * 262144, db + l * D_,
                                                 x, x, nullptr, 1024, 256, 2 | 8);
  }
  k_ln<<<dim3(BM_TOT / 4), blk, 0, stream>>>(x, lnfw, lnfb, xn_b);
  // merged: final projection (64 blocks) + s head (544 blocks), independent workloads
  k_tail<<<dim3(608), blk512, 0, stream>>>(xn_b, fwt, finb, outx,
                                           q_b, k_b, snw, snb, sfw, sfb, outs);
}